// Round 3
// baseline (952.992 us; speedup 1.0000x reference)
//
#include <hip/hip_runtime.h>
#include <stdint.h>

typedef __bf16 bf16_t;
typedef __bf16 bf16x8 __attribute__((ext_vector_type(8)));
typedef __bf16 bf16x4 __attribute__((ext_vector_type(4)));
typedef float  f32x4  __attribute__((ext_vector_type(4)));
typedef uint32_t u32x4 __attribute__((ext_vector_type(4)));

constexpr int cBS = 64, cP = 512, cD = 1024, cDWM = 1024, cH = 16, cHD = 64, cW = 128;
constexpr int cVTP = 672;           // padded p-extent of Vt (sp = p + 128, max used 656)
constexpr int cM = cBS * cP;        // 32768
constexpr float cSCALE = 0.125f;    // 1/sqrt(64)

__device__ __forceinline__ void gld_lds16(const void* g, void* l) {
#if __has_builtin(__builtin_amdgcn_global_load_lds)
  __builtin_amdgcn_global_load_lds(
      (__attribute__((address_space(1))) void*)g,
      (__attribute__((address_space(3))) void*)l, 16, 0, 0);
#else
  *(bf16x8*)l = *(const bf16x8*)g;
#endif
}

// ---------------------------------------------------------------------------
// fp32 -> bf16 conversion of X
__global__ void cvt_x_k(const float* __restrict__ X, bf16_t* __restrict__ Y, int n) {
  int i = (blockIdx.x * blockDim.x + threadIdx.x) * 4;
  if (i >= n) return;
  float4 v = *(const float4*)(X + i);
  bf16x4 o;
  o[0] = (bf16_t)v.x; o[1] = (bf16_t)v.y; o[2] = (bf16_t)v.z; o[3] = (bf16_t)v.w;
  *(bf16x4*)(Y + i) = o;
}

// transpose + convert the four 1024x1024 weights: W[k][n] fp32 -> Wt[n][k] bf16
__global__ void cvt_wt_k(const float* __restrict__ W0, const float* __restrict__ W1,
                         const float* __restrict__ W2, const float* __restrict__ W3,
                         bf16_t* __restrict__ T0, bf16_t* __restrict__ T1,
                         bf16_t* __restrict__ T2, bf16_t* __restrict__ T3) {
  __shared__ float tile[32][33];
  const float* Wsrc; bf16_t* Tdst;
  switch (blockIdx.z) {
    case 0: Wsrc = W0; Tdst = T0; break;
    case 1: Wsrc = W1; Tdst = T1; break;
    case 2: Wsrc = W2; Tdst = T2; break;
    default: Wsrc = W3; Tdst = T3; break;
  }
  const int n0 = blockIdx.x * 32, k0 = blockIdx.y * 32;
  const int c = threadIdx.x & 31, r8 = threadIdx.x >> 5;
#pragma unroll
  for (int q = 0; q < 4; ++q) {
    int row = r8 + q * 8;
    tile[row][c] = Wsrc[(size_t)(k0 + row) * 1024 + n0 + c];
  }
  __syncthreads();
#pragma unroll
  for (int q = 0; q < 4; ++q) {
    int row = r8 + q * 8;
    Tdst[(size_t)(n0 + row) * 1024 + k0 + c] = (bf16_t)tile[c][row];
  }
}

// r[b][t] = index of last reset at-or-before t (0 if none): parallel max-scan
__global__ void resets2_k(const int* __restrict__ mask, int* __restrict__ r) {
  __shared__ int sm[cP];
  const int b = blockIdx.x, t = threadIdx.x;
  sm[t] = mask[b * cP + t] ? t : 0;
  __syncthreads();
#pragma unroll
  for (int d = 1; d < cP; d <<= 1) {
    int u = (t >= d) ? sm[t - d] : 0;
    __syncthreads();
    if (u > sm[t]) sm[t] = u;
    __syncthreads();
  }
  r[b * cP + t] = sm[t];
}

// ---------------------------------------------------------------------------
// Fused QKV GEMM, 256x256 tile, 8-phase REG-STAGED pipeline (T3+T4+T5+T14),
// fragment-order conflict-free LDS, ONE barrier per phase.
// C[M][3072] = A[M][1024] * Wt[3072][1024]^T.
// Seg 0 -> Q head-major [b][h][p][hd], 1 -> K head-major, 2 -> Vt [b][h][hd][sp].
//
// LDS (128 KiB): buf{0,1} x 64 KiB; within buf: A kh0|A kh1|B kh0|B kh1
// (16 KiB each, A at +0/+16K, B at +32K/+48K). Each 16 KiB region holds
// 256 rows x 32 bf16 in FRAGMENT ORDER (16 subtiles of 16 rows; element
// (row r, 16B k-chunk c) at subtile*1024 + (c*16+(r&15))*16) -> a wave's
// frag ds_read_b128 covers 1024 consecutive bytes (0 bank conflicts, R2).
//
// Staging is global->REG->ds_write (no global_load_lds): the ds_write of a
// slot loaded 2 phases earlier gives a PRECISE compiler-inserted counted
// vmcnt wait (never a drain), and LDS-DMA alias-tracking can't force
// vmcnt(0) ahead of frag reads. Slot regs ping-pong on phase parity.
//
// Per phase k (compute C[k], write slot[k-2], issue slot[k]):
//   [ds_write slot k-2] [global_load_dwordx4 x2 -> regs (slot k)]
//   [frag ds_reads] [setprio(1) MFMA x16 setprio(0)]
//   [asm: s_waitcnt lgkmcnt(0); s_barrier]            <- ONE barrier/phase
// Same-phase write-region ∩ read-region = ∅ for all 8 phases (checked), so
// the leading barrier is unnecessary; adjacent phases are barrier-separated.
// Schedule (iter t: j1=2t+1, j2=2t+2, j3=2t+3; compute buf0=tile 2t, buf1=j1):
//  k  compute      write(slot k-2)   issue(slot k)
//  0  F(0,kh0)     (1,0,A,j1)        (A,j1,kh1)
//  1  R(0,kh0)     (1,0,B,j1)        (B,j1,kh1)
//  2  F(0,kh1)     (1,1,A,j1)        (A,j2,kh0)
//  3  R(0,kh1)     (1,1,B,j1)        (B,j2,kh0)
//  4  F(1,kh0)     (0,0,A,j2)        (A,j2,kh1)
//  5  R(1,kh0)     (0,0,B,j2)        (B,j2,kh1)
//  6  F(1,kh1)     (0,1,A,j2)        (A,j3,kh0)
//  7  R(1,kh1)     (0,1,B,j2)        (B,j3,kh0)
// F loads 4 B-frags (persistent) + 4 A-frags, MFMA acc rows 0..3;
// R loads 4 A-frags, reuses B, MFMA acc rows 4..7.
__global__ __launch_bounds__(512, 2)
void gemm_qkv8_k(const bf16_t* __restrict__ A, const bf16_t* __restrict__ Wt,
                 const float* __restrict__ bq, const float* __restrict__ bk,
                 const float* __restrict__ bvv,
                 bf16_t* __restrict__ Qh, bf16_t* __restrict__ Kh,
                 bf16_t* __restrict__ Vt) {
  __shared__ __align__(16) char LDS[131072];
  const int tid = threadIdx.x;
  const int wid = tid >> 6, ln = tid & 63;
  const int ln15 = ln & 15, g4 = ln >> 4;
  const int wr = wid >> 2, wc = wid & 3;   // wave -> (row half, col quarter)

  // XCD swizzle: per-XCD m-slice, n-fastest so the A-panel stays L2-resident
  const int g = blockIdx.x + 12 * blockIdx.y;   // [0, 1536)
  const int xcd = g & 7, s = g >> 3;            // s in [0, 192)
  const int nb = s % 12, mloc = s / 12;         // mloc in [0, 16)
  const int m0 = (xcd * 16 + mloc) * 256, n0 = nb * 256;

  const bf16_t* Ab = A + (size_t)m0 * 1024;
  const bf16_t* Bb = Wt + (size_t)n0 * 1024;

  // staging map: thread covers LDS chunks q = tid and q + 512 of a region.
  // q -> subtile q>>6, row-in-subtile q&15, k-chunk (q>>4)&3
  // global element = ((q>>6)*16 + (q&15))*1024 + ((q>>4)&3)*8 (+128 rows for +512)
  const int srow = (tid >> 6) * 16 + (tid & 15);    // 0..127
  const int kc = (tid >> 4) & 3;
  const size_t aoff = (size_t)srow * 1024 + (size_t)(kc * 8);

  // frag read lane addressing: 1024 consecutive bytes per subtile
  const int lane16 = (g4 * 16 + ln15) * 16;
  const int abase = (wr * 8) * 1024 + lane16;   // + mi*1024 (+4096 for R)
  const int bbase = (wc * 4) * 1024 + lane16;   // + nj*1024, within B region

  f32x4 acc[8][4];
#pragma unroll
  for (int i = 0; i < 8; ++i)
#pragma unroll
    for (int j = 0; j < 4; ++j) acc[i][j] = {0.f, 0.f, 0.f, 0.f};

  bf16x8 bqf[4];                 // persistent B fragments (F loads, R reuses)
  u32x4 p0a, p0b, p1a, p1b;      // ping-pong staging pairs (parity = phase&1)

#define GLOADP(p, BASE, j, kh) do {                                           \
    const bf16_t* g_ = (BASE) + (size_t)((j) * 64 + (kh) * 32) + aoff;        \
    p##a = *(const u32x4*)g_;                                                 \
    p##b = *(const u32x4*)(g_ + (size_t)128 * 1024);                          \
  } while (0)

#define LDSW(p, buf, kh, isB) do {                                            \
    char* w_ = LDS + (buf) * 65536 + (kh) * 16384 + (isB) * 32768 + tid * 16; \
    *(u32x4*)w_ = p##a;                                                       \
    *(u32x4*)(w_ + 8192) = p##b;                                              \
  } while (0)

#define FENCE asm volatile("s_waitcnt lgkmcnt(0)\ns_barrier" ::: "memory")
#define NOP ((void)0)

#define PHASE_F(buf, kh, WR, ISS) do {                                        \
    WR;                                                                       \
    ISS;                                                                      \
    const char* Ar_ = LDS + (buf) * 65536 + (kh) * 16384 + abase;             \
    const char* Br_ = LDS + (buf) * 65536 + (kh) * 16384 + 32768 + bbase;     \
    bf16x8 af_[4];                                                            \
    af_[0] = *(const bf16x8*)(Ar_);                                           \
    af_[1] = *(const bf16x8*)(Ar_ + 1024);                                    \
    af_[2] = *(const bf16x8*)(Ar_ + 2048);                                    \
    af_[3] = *(const bf16x8*)(Ar_ + 3072);                                    \
    bqf[0] = *(const bf16x8*)(Br_);                                           \
    bqf[1] = *(const bf16x8*)(Br_ + 1024);                                    \
    bqf[2] = *(const bf16x8*)(Br_ + 2048);                                    \
    bqf[3] = *(const bf16x8*)(Br_ + 3072);                                    \
    __builtin_amdgcn_s_setprio(1);                                            \
    _Pragma("unroll")                                                         \
    for (int mi_ = 0; mi_ < 4; ++mi_)                                         \
      _Pragma("unroll")                                                       \
      for (int nj_ = 0; nj_ < 4; ++nj_)                                       \
        acc[mi_][nj_] = __builtin_amdgcn_mfma_f32_16x16x32_bf16(              \
            af_[mi_], bqf[nj_], acc[mi_][nj_], 0, 0, 0);                      \
    __builtin_amdgcn_s_setprio(0);                                            \
    FENCE;                                                                    \
  } while (0)

#define PHASE_R(buf, kh, WR, ISS) do {                                        \
    WR;                                                                       \
    ISS;                                                                      \
    const char* Ar_ = LDS + (buf) * 65536 + (kh) * 16384 + abase + 4096;      \
    bf16x8 af_[4];                                                            \
    af_[0] = *(const bf16x8*)(Ar_);                                           \
    af_[1] = *(const bf16x8*)(Ar_ + 1024);                                    \
    af_[2] = *(const bf16x8*)(Ar_ + 2048);                                    \
    af_[3] = *(const bf16x8*)(Ar_ + 3072);                                    \
    __builtin_amdgcn_s_setprio(1);                                            \
    _Pragma("unroll")                                                         \
    for (int mi_ = 0; mi_ < 4; ++mi_)                                         \
      _Pragma("unroll")                                                       \
      for (int nj_ = 0; nj_ < 4; ++nj_)                                       \
        acc[4 + mi_][nj_] = __builtin_amdgcn_mfma_f32_16x16x32_bf16(          \
            af_[mi_], bqf[nj_], acc[4 + mi_][nj_], 0, 0, 0);                  \
    __builtin_amdgcn_s_setprio(0);                                            \
    FENCE;                                                                    \
  } while (0)

  // prologue: tile0 -> buf0 (both kh); prime pipeline with (A,1,kh0),(B,1,kh0)
  {
    u32x4 q0a, q0b, q1a, q1b;
    GLOADP(p0, Ab, 0, 0); GLOADP(p1, Bb, 0, 0);
    GLOADP(q0, Ab, 0, 1); GLOADP(q1, Bb, 0, 1);
    LDSW(p0, 0, 0, 0); LDSW(p1, 0, 0, 1);
    LDSW(q0, 0, 1, 0); LDSW(q1, 0, 1, 1);
    GLOADP(p0, Ab, 1, 0); GLOADP(p1, Bb, 1, 0);
    FENCE;
  }

  for (int t = 0; t < 7; ++t) {
    const int j1 = 2 * t + 1, j2 = 2 * t + 2, j3 = 2 * t + 3;
    PHASE_F(0, 0, LDSW(p0, 1, 0, 0), GLOADP(p0, Ab, j1, 1));
    PHASE_R(0, 0, LDSW(p1, 1, 0, 1), GLOADP(p1, Bb, j1, 1));
    PHASE_F(0, 1, LDSW(p0, 1, 1, 0), GLOADP(p0, Ab, j2, 0));
    PHASE_R(0, 1, LDSW(p1, 1, 1, 1), GLOADP(p1, Bb, j2, 0));
    PHASE_F(1, 0, LDSW(p0, 0, 0, 0), GLOADP(p0, Ab, j2, 1));
    PHASE_R(1, 0, LDSW(p1, 0, 0, 1), GLOADP(p1, Bb, j2, 1));
    PHASE_F(1, 1, LDSW(p0, 0, 1, 0), GLOADP(p0, Ab, j3, 0));
    PHASE_R(1, 1, LDSW(p1, 0, 1, 1), GLOADP(p1, Bb, j3, 0));
  }
  // tail: compute tiles 14 (buf0) and 15 (buf1); finish staging tile 15
  PHASE_F(0, 0, LDSW(p0, 1, 0, 0), GLOADP(p0, Ab, 15, 1));
  PHASE_R(0, 0, LDSW(p1, 1, 0, 1), GLOADP(p1, Bb, 15, 1));
  PHASE_F(0, 1, LDSW(p0, 1, 1, 0), NOP);
  PHASE_R(0, 1, LDSW(p1, 1, 1, 1), NOP);
  PHASE_F(1, 0, NOP, NOP);
  PHASE_R(1, 0, NOP, NOP);
  PHASE_F(1, 1, NOP, NOP);
  PHASE_R(1, 1, NOP, NOP);

#undef PHASE_F
#undef PHASE_R
#undef GLOADP
#undef LDSW
#undef FENCE
#undef NOP

  const int seg = n0 >> 10;                      // block-uniform: 0=Q 1=K 2=V
  const float* bias = (seg == 0) ? bq : (seg == 1) ? bk : bvv;
  bf16_t* QK = (seg == 0) ? Qh : Kh;
#pragma unroll
  for (int mi = 0; mi < 8; ++mi) {
    const int rbase = m0 + wr * 128 + mi * 16 + g4 * 4;
    const int b = rbase >> 9, pb = rbase & 511;
#pragma unroll
    for (int nj = 0; nj < 4; ++nj) {
      const int col = n0 + wc * 64 + nj * 16 + ln15;
      const int cl = col & 1023;
      const int h = cl >> 6, hd = cl & 63;
      const float bv = bias[cl];
      if (seg < 2) {
        // head-major: [b][h][p][hd]
#pragma unroll
        for (int r = 0; r < 4; ++r)
          QK[(((size_t)(b * cH + h)) * cP + pb + r) * cHD + hd] =
              (bf16_t)(acc[mi][nj][r] + bv);
      } else {
        bf16x4 pk;
#pragma unroll
        for (int r = 0; r < 4; ++r) pk[r] = (bf16_t)(acc[mi][nj][r] + bv);
        *(bf16x4*)(Vt + ((size_t)((b * cH + h) * cHD + hd)) * cVTP + 128 + pb) = pk;
      }
    }
  }
}

// Output-projection GEMM (fp32 out), 128x128 tile + XCD swizzle
__global__ __launch_bounds__(256)
void gemm_bt_k(const bf16_t* __restrict__ A, const bf16_t* __restrict__ Bt,
               const float* __restrict__ bias, float* __restrict__ C,
               int M, int N, int K) {
  __shared__ __align__(16) bf16_t As[2][128 * 32];
  __shared__ __align__(16) bf16_t Bs[2][128 * 32];
  const int tid = threadIdx.x;
  const int wv = tid >> 6, ln = tid & 63;
  const int ln15 = ln & 15, g4 = ln >> 4;

  const int g = blockIdx.x + 8 * blockIdx.y;    // [0, 2048)
  const int xcd = g & 7, s = g >> 3;            // s in [0, 256)
  const int nb = s & 7, mloc = s >> 3;          // mloc in [0, 32)
  const int m0 = (xcd * 32 + mloc) * 128, n0 = nb * 128;

  const int wm = (wv >> 1) * 64, wn = (wv & 1) * 64;
  const bf16_t* Ab = A + (size_t)m0 * K;
  const bf16_t* Bb = Bt + (size_t)n0 * K;

  auto stage = [&](const bf16_t* G, bf16_t* L, int k0) {
#pragma unroll
    for (int gg = 0; gg < 2; ++gg) {
      int slot = gg * 256 + tid;
      gld_lds16(G + (size_t)(slot >> 2) * K + (k0 + (slot & 3) * 8), L + slot * 8);
    }
  };

  f32x4 acc[4][4];
#pragma unroll
  for (int i = 0; i < 4; ++i)
#pragma unroll
    for (int j = 0; j < 4; ++j) acc[i][j] = {0.f, 0.f, 0.f, 0.f};

  const int nk = K >> 5;
  stage(Ab, As[0], 0);
  stage(Bb, Bs[0], 0);
  for (int kt = 0; kt < nk; ++kt) {
    __syncthreads();
    if (kt + 1 < nk) {
      stage(Ab, As[(kt + 1) & 1], (kt + 1) * 32);
      stage(Bb, Bs[(kt + 1) & 1], (kt + 1) * 32);
    }
    const bf16_t* Asb = As[kt & 1];
    const bf16_t* Bsb = Bs[kt & 1];
    bf16x8 af[4], bfr[4];
#pragma unroll
    for (int i = 0; i < 4; ++i)
      af[i] = *(const bf16x8*)(Asb + (wm + i * 16 + ln15) * 32 + g4 * 8);
#pragma unroll
    for (int j = 0; j < 4; ++j)
      bfr[j] = *(const bf16x8*)(Bsb + (wn + j * 16 + ln15) * 32 + g4 * 8);
#pragma unroll
    for (int i = 0; i < 4; ++i)
#pragma unroll
      for (int j = 0; j < 4; ++j)
        acc[i][j] = __builtin_amdgcn_mfma_f32_16x16x32_bf16(af[i], bfr[j], acc[i][j], 0, 0, 0);
  }

#pragma unroll
  for (int i = 0; i < 4; ++i) {
    const int rbase = m0 + wm + i * 16 + g4 * 4;
#pragma unroll
    for (int j = 0; j < 4; ++j) {
      const int col = n0 + wn + j * 16 + ln15;
      const float bv = bias[col];
#pragma unroll
      for (int r = 0; r < 4; ++r)
        C[(size_t)(rbase + r) * N + col] = acc[i][j][r] + bv;
    }
  }
}

// ---------------------------------------------------------------------------
// Windowed attention v3: block = (head, batch, t-chunk); 4 waves each own a
// 16-token tile; 2 iterations cover the 128-token chunk. Q/K head-major.
__global__ __launch_bounds__(256)
void attn3_k(const bf16_t* __restrict__ Q, const bf16_t* __restrict__ Kv,
             const bf16_t* __restrict__ Vt, const int* __restrict__ rr,
             bf16_t* __restrict__ O) {
  __shared__ __align__(16) bf16_t Pl[4][16][168];
  const int tid = threadIdx.x;
  const int wv = tid >> 6, ln = tid & 63, ln15 = ln & 15, g4 = ln >> 4;
  const int h = blockIdx.x, b = blockIdx.y, tc = blockIdx.z;
  bf16_t(*Pw)[168] = Pl[wv];
  const bf16_t* vb = Vt + ((size_t)(b * cH + h)) * cHD * cVTP;
  const bf16_t* qb = Q + ((size_t)(b * cH + h)) * cP * cHD;
  const bf16_t* kb = Kv + ((size_t)(b * cH + h)) * cP * cHD;

  for (int sub = 0; sub < 2; ++sub) {
    const int t0 = (tc * 2 + sub) * 64 + wv * 16;
    const int sbase = t0 - 128;

    int rv[4];
#pragma unroll
    for (int r = 0; r < 4; ++r) rv[r] = rr[b * cP + t0 + g4 * 4 + r];

    // Q A-frag: m = ln15 (t), k = g4*8+j (hd)
    const bf16_t* qp = qb + (size_t)(t0 + ln15) * cHD + g4 * 8;
    const bf16x8 qa0 = *(const bf16x8*)qp;
    const bf16x8 qa1 = *(const bf16x8*)(qp + 32);

    // QK^T over 9 s-chunks of 16 (s in [t0-128, t0+15])
    f32x4 lg[9];
#pragma unroll
    for (int c = 0; c < 9; ++c) {
      const int s = sbase + c * 16 + ln15;  // B-frag n = ln15 (s), k = hd
      bf16x8 k0v, k1v;
      if ((unsigned)s < (unsigned)cP) {
        const bf16_t* kp = kb + (size_t)s * cHD + g4 * 8;
        k0v = *(const bf16x8*)kp;
        k1v = *(const bf16x8*)(kp + 32);
      } else {
#pragma unroll
        for (int z = 0; z < 8; ++z) { k0v[z] = (bf16_t)0.f; k1v[z] = (bf16_t)0.f; }
      }
      f32x4 a = {0.f, 0.f, 0.f, 0.f};
      a = __builtin_amdgcn_mfma_f32_16x16x32_bf16(qa0, k0v, a, 0, 0, 0);
      a = __builtin_amdgcn_mfma_f32_16x16x32_bf16(qa1, k1v, a, 0, 0, 0);
      lg[c] = a;
    }

    // mask + scale; C layout: col(s)=ln15, row(t)=g4*4+reg
    float mx[4] = {-1e30f, -1e30f, -1e30f, -1e30f};
#pragma unroll
    for (int c = 0; c < 9; ++c)
#pragma unroll
      for (int r = 0; r < 4; ++r) {
        const int s = sbase + c * 16 + ln15;
        const int t = t0 + g4 * 4 + r;
        const bool ok = (s >= rv[r]) && (s <= t) && (t - s < cW);
        const float l = ok ? lg[c][r] * cSCALE : -1e30f;
        lg[c][r] = l;
        mx[r] = fmaxf(mx[r], l);
      }
#pragma unroll
    for (int r = 0; r < 4; ++r) {
      mx[r] = fmaxf(mx[r], __shfl_xor(mx[r], 1));
      mx[r] = fmaxf(mx[r], __shfl_xor(mx[r], 2));
      mx[r] = fmaxf(mx[r], __shfl_xor(mx[r], 4));
      mx[r] = fmaxf(mx[r], __shfl_xor(mx[r], 8));
    }
    float sm[4] = {0.f, 0.f, 0.f, 0.f};
#pragma unroll
    for (int c = 0; c < 9; ++c)
#pragma unroll
      for (int r = 0; r < 4; ++r) {
        const float e = __expf(lg[c][r] - mx[r]);
        lg[c][r] = e;
        sm[r] += e;
      }
#pragma unroll
    for (int r = 0; r < 4; ++r) {
      sm[r] += __shfl_xor(sm[r], 1);
      sm[r] += __shfl_xor(sm[r], 2);
      sm[r] += __shfl_xor(sm[r], 4);
      sm[r] += __shfl_xor(sm[r], 8);
    }
    float inv[4];
#pragma unroll
    for (int r = 0; r < 4; ++r) inv[r] = 1.f / sm[r];

    // P -> LDS (C-layout write), zero pad cols 144..159 for the 5th PV chunk
#pragma unroll
    for (int c = 0; c < 9; ++c)
#pragma unroll
      for (int r = 0; r < 4; ++r)
        Pw[g4 * 4 + r][c * 16 + ln15] = (bf16_t)(lg[c][r] * inv[r]);
#pragma unroll
    for (int z = 0; z < 4; ++z)
      Pw[ln15][144 + g4 * 4 + z] = (bf16_t)0.f;

    // PV: A = P (m=t, k=s from LDS), B = Vt rows (n=hd, k=s contiguous)
    f32x4 oacc[4];
#pragma unroll
    for (int j = 0; j < 4; ++j) oacc[j] = {0.f, 0.f, 0.f, 0.f};
#pragma unroll
    for (int c2 = 0; c2 < 5; ++c2) {
      const bf16x8 pa = *(const bf16x8*)(&Pw[ln15][c2 * 32 + g4 * 8]);
#pragma unroll
      for (int j = 0; j < 4; ++j) {
        const bf16x8 vf =
            *(const bf16x8*)(vb + (size_t)(j * 16 + ln15) * cVTP + (t0 + c2 * 32 + g4 * 8));
        oacc[j] = __builtin_amdgcn_mfma_f32_16x16x32_bf16(pa, vf, oacc[j], 0, 0, 0);
      }
    }
#pragma unroll
    for (int j = 0; j < 4; ++j) {
      const int col = h * cHD + j * 16 + ln15;
#pragma unroll
      for (int r = 0; r < 4; ++r)
        O[((size_t)(b * cP + t0 + g4 * 4 + r)) * cDWM + col] = (bf16_t)oacc[j][r];
    }
  }
}

// ---------------------------------------------------------------------------
extern "C" void kernel_launch(void* const* d_in, const int* in_sizes, int n_in,
                              void* d_out, int out_size, void* d_ws, size_t ws_size,
                              hipStream_t stream) {
  (void)in_sizes; (void)n_in; (void)out_size; (void)ws_size;
  const float* x  = (const float*)d_in[0];
  const int* mask = (const int*)d_in[1];
  const float* Wq = (const float*)d_in[2];
  const float* bq = (const float*)d_in[3];
  const float* Wk = (const float*)d_in[4];
  const float* bk = (const float*)d_in[5];
  const float* Wv = (const float*)d_in[6];
  const float* bv = (const float*)d_in[7];
  const float* Wo = (const float*)d_in[8];
  const float* bo = (const float*)d_in[9];
  float* out = (float*)d_out;

  char* ws = (char*)d_ws;
  size_t off = 0;
  bf16_t* Xbf = (bf16_t*)(ws + off); off += (size_t)cM * cD * 2;          // 64 MiB
  bf16_t* Wqt = (bf16_t*)(ws + off); off += (size_t)cD * cDWM * 2;        // contiguous
  bf16_t* Wkt = (bf16_t*)(ws + off); off += (size_t)cD * cDWM * 2;        //   [3072][1024]
  bf16_t* Wvt = (bf16_t*)(ws + off); off += (size_t)cD * cDWM * 2;        //   QKV block
  bf16_t* Wot = (bf16_t*)(ws + off); off += (size_t)cDWM * cD * 2;
  bf16_t* Qh  = (bf16_t*)(ws + off); off += (size_t)cM * cDWM * 2;        // 64 MiB
  bf16_t* Kh  = (bf16_t*)(ws + off); off += (size_t)cM * cDWM * 2;        // 64 MiB
  bf16_t* Vt  = (bf16_t*)(ws + off); off += (size_t)cBS * cH * cHD * cVTP * 2;  // 84 MiB
  int* rbuf   = (int*)(ws + off);    off += (size_t)cBS * cP * 4;
  bf16_t* Ob  = Xbf;  // X no longer needed after the QKV projection

  cvt_x_k<<<(cM * cD / 4 + 255) / 256, 256, 0, stream>>>(x, Xbf, cM * cD);
  cvt_wt_k<<<dim3(32, 32, 4), 256, 0, stream>>>(Wq, Wk, Wv, Wo, Wqt, Wkt, Wvt, Wot);
  resets2_k<<<cBS, cP, 0, stream>>>(mask, rbuf);

  gemm_qkv8_k<<<dim3(12, 128), 512, 0, stream>>>(Xbf, Wqt, bq, bk, bv, Qh, Kh, Vt);

  attn3_k<<<dim3(cH, cBS, 4), 256, 0, stream>>>(Qh, Kh, Vt, rbuf, Ob);

  gemm_bt_k<<<dim3(8, 256), 256, 0, stream>>>(Ob, Wot, bo, out, cM, cD, cDWM);
}

// Round 4
// 546.652 us; speedup vs baseline: 1.7433x; 1.7433x over previous
//
#include <hip/hip_runtime.h>
#include <stdint.h>

typedef __bf16 bf16_t;
typedef __bf16 bf16x8 __attribute__((ext_vector_type(8)));
typedef __bf16 bf16x4 __attribute__((ext_vector_type(4)));
typedef float  f32x4  __attribute__((ext_vector_type(4)));
typedef __attribute__((address_space(3))) char lds_char;

constexpr int cBS = 64, cP = 512, cD = 1024, cDWM = 1024, cH = 16, cHD = 64, cW = 128;
constexpr int cVTP = 672;           // padded p-extent of Vt (sp = p + 128, max used 656)
constexpr int cM = cBS * cP;        // 32768
constexpr float cSCALE = 0.125f;    // 1/sqrt(64)

__device__ __forceinline__ void gld_lds16(const void* g, void* l) {
#if __has_builtin(__builtin_amdgcn_global_load_lds)
  __builtin_amdgcn_global_load_lds(
      (__attribute__((address_space(1))) void*)g,
      (__attribute__((address_space(3))) void*)l, 16, 0, 0);
#else
  *(bf16x8*)l = *(const bf16x8*)g;
#endif
}

// ---------------------------------------------------------------------------
// fp32 -> bf16 conversion of X
__global__ void cvt_x_k(const float* __restrict__ X, bf16_t* __restrict__ Y, int n) {
  int i = (blockIdx.x * blockDim.x + threadIdx.x) * 4;
  if (i >= n) return;
  float4 v = *(const float4*)(X + i);
  bf16x4 o;
  o[0] = (bf16_t)v.x; o[1] = (bf16_t)v.y; o[2] = (bf16_t)v.z; o[3] = (bf16_t)v.w;
  *(bf16x4*)(Y + i) = o;
}

// transpose + convert the four 1024x1024 weights: W[k][n] fp32 -> Wt[n][k] bf16
__global__ void cvt_wt_k(const float* __restrict__ W0, const float* __restrict__ W1,
                         const float* __restrict__ W2, const float* __restrict__ W3,
                         bf16_t* __restrict__ T0, bf16_t* __restrict__ T1,
                         bf16_t* __restrict__ T2, bf16_t* __restrict__ T3) {
  __shared__ float tile[32][33];
  const float* Wsrc; bf16_t* Tdst;
  switch (blockIdx.z) {
    case 0: Wsrc = W0; Tdst = T0; break;
    case 1: Wsrc = W1; Tdst = T1; break;
    case 2: Wsrc = W2; Tdst = T2; break;
    default: Wsrc = W3; Tdst = T3; break;
  }
  const int n0 = blockIdx.x * 32, k0 = blockIdx.y * 32;
  const int c = threadIdx.x & 31, r8 = threadIdx.x >> 5;
#pragma unroll
  for (int q = 0; q < 4; ++q) {
    int row = r8 + q * 8;
    tile[row][c] = Wsrc[(size_t)(k0 + row) * 1024 + n0 + c];
  }
  __syncthreads();
#pragma unroll
  for (int q = 0; q < 4; ++q) {
    int row = r8 + q * 8;
    Tdst[(size_t)(n0 + row) * 1024 + k0 + c] = (bf16_t)tile[c][row];
  }
}

// r[b][t] = index of last reset at-or-before t (0 if none): parallel max-scan
__global__ void resets2_k(const int* __restrict__ mask, int* __restrict__ r) {
  __shared__ int sm[cP];
  const int b = blockIdx.x, t = threadIdx.x;
  sm[t] = mask[b * cP + t] ? t : 0;
  __syncthreads();
#pragma unroll
  for (int d = 1; d < cP; d <<= 1) {
    int u = (t >= d) ? sm[t - d] : 0;
    __syncthreads();
    if (u > sm[t]) sm[t] = u;
    __syncthreads();
  }
  r[b * cP + t] = sm[t];
}

// ---------------------------------------------------------------------------
// Fused QKV GEMM, 256x256 tile, 8-phase pipelined (T3+T4+T5), fragment-order
// conflict-free LDS (R2), global_load_lds staging, and ASM frag ds_reads so
// the compiler's waitcnt pass cannot insert vmcnt(0) drains for LDS-DMA
// aliasing -- the only VMEM waits are the counted VM4s (T4, m218 mechanism).
// C[M][3072] = A[M][1024] * Wt[3072][1024]^T.
// Seg 0 -> Q head-major [b][h][p][hd], 1 -> K head-major, 2 -> Vt [b][h][hd][sp].
//
// LDS (128 KiB): per dbuf (64 KiB): A kh0 [0,16K) | A kh1 [16K,32K) |
//                                   B kh0 [32K,48K) | B kh1 [48K,64K)
// Each 16 KiB half: 256 rows x 32 bf16 in FRAGMENT ORDER: 16 subtiles of 16
// rows; element (row r, 16B k-chunk c) at subtile*1024 + (c*16+(r&15))*16.
// A wave's frag read covers 1024 consecutive bytes -> 0 bank conflicts
// (verified R2: SQ_LDS_BANK_CONFLICT = 0). LDS dest of global_load_lds stays
// linear (tid*16); the GLOBAL source is permuted to match (rule #21).
//
// Schedule per iteration (2 K-tiles j0=2t -> buf0, j1=2t+1 -> buf1):
//  P1 F(buf0,kh0) stage A(j1,kh0)->buf1      P5 F(buf1,kh0) stage A(j0+2,kh0)->buf0
//  P2 R(buf0,kh0) stage B(j1,kh0)  vmcnt(4)  P6 R(buf1,kh0) stage B(j0+2,kh0) vmcnt(4)
//  P3 F(buf0,kh1) stage A(j1,kh1)            P7 F(buf1,kh1) stage A(j0+2,kh1)
//  P4 R(buf0,kh1) stage B(j1,kh1)  vmcnt(4)  P8 R(buf1,kh1) stage B(j0+2,kh1) vmcnt(4)
// F: asm-loads 4 B-frags (persistent regs) + 4 A-frags, 16 MFMA (acc 0..3).
// R: asm-loads 4 A-frags only, reuses B regs, 16 MFMA (acc 4..7).
// Each vmcnt(4) drains exactly the 2 stages the next k-half needs, keeping
// 2 stages (4 loads) in flight; never drains to 0 in the main loop.
__global__ __launch_bounds__(512, 2)
void gemm_qkv8_k(const bf16_t* __restrict__ A, const bf16_t* __restrict__ Wt,
                 const float* __restrict__ bq, const float* __restrict__ bk,
                 const float* __restrict__ bvv,
                 bf16_t* __restrict__ Qh, bf16_t* __restrict__ Kh,
                 bf16_t* __restrict__ Vt) {
  __shared__ __align__(16) char LDS[131072];
  const int tid = threadIdx.x;
  const int wid = tid >> 6, ln = tid & 63;
  const int ln15 = ln & 15, g4 = ln >> 4;
  const int wr = wid >> 2, wc = wid & 3;   // wave -> (row half, col quarter)

  // XCD swizzle: per-XCD m-slice, n-fastest so the A-panel stays L2-resident
  const int g = blockIdx.x + 12 * blockIdx.y;   // [0, 1536)
  const int xcd = g & 7, s = g >> 3;            // s in [0, 192)
  const int nb = s % 12, mloc = s / 12;         // mloc in [0, 16)
  const int m0 = (xcd * 16 + mloc) * 256, n0 = nb * 256;

  const bf16_t* Ab = A + (size_t)m0 * 1024;
  const bf16_t* Bb = Wt + (size_t)n0 * 1024;

  // staging: thread covers LDS chunks q = tid and q+512 of a 16 KiB region.
  // q -> subtile q>>6, row-in-subtile q&15, k-chunk (q>>4)&3
  // global element = ((q>>6)*16 + (q&15))*1024 + ((q>>4)&3)*8 (+128 rows @ +512)
  const int srow = (tid >> 6) * 16 + (tid & 15);    // 0..127
  const int kc = (tid >> 4) & 3;
  const size_t aoff = (size_t)srow * 1024 + (size_t)(kc * 8);
  char* const lbase = LDS + tid * 16;

  // 32-bit LDS byte address for asm ds_read (AS3 offset)
  const uint32_t ldsb = (uint32_t)(size_t)(lds_char*)LDS;
  const int lane16 = (g4 * 16 + ln15) * 16;
  const uint32_t abase = ldsb + (uint32_t)((wr * 8) * 1024 + lane16);
  const uint32_t bbase = ldsb + 32768u + (uint32_t)((wc * 4) * 1024 + lane16);

  f32x4 acc[8][4];
#pragma unroll
  for (int i = 0; i < 8; ++i)
#pragma unroll
    for (int j = 0; j < 4; ++j) acc[i][j] = {0.f, 0.f, 0.f, 0.f};

  bf16x8 bqf[4];   // persistent B fragments (loaded in F, reused in R)

#define DSR(d, a, OFF) \
  asm volatile("ds_read_b128 %0, %1 offset:" #OFF : "=v"(d) : "v"(a))

#define STAGE_A(buf, kh, j) do {                                              \
    const bf16_t* gp_ = Ab + (size_t)((j) * 64 + (kh) * 32) + aoff;           \
    char* lp_ = lbase + (buf) * 65536 + (kh) * 16384;                         \
    gld_lds16(gp_, lp_);                                                      \
    gld_lds16(gp_ + (size_t)128 * 1024, lp_ + 8192);                          \
  } while (0)

#define STAGE_B(buf, kh, j) do {                                              \
    const bf16_t* gp_ = Bb + (size_t)((j) * 64 + (kh) * 32) + aoff;           \
    char* lp_ = lbase + (buf) * 65536 + (kh) * 16384 + 32768;                 \
    gld_lds16(gp_, lp_);                                                      \
    gld_lds16(gp_ + (size_t)128 * 1024, lp_ + 8192);                          \
  } while (0)

#define NOSTAGE ((void)0)
#define VM4 asm volatile("s_waitcnt vmcnt(4)" ::: "memory")
#define VM0 asm volatile("s_waitcnt vmcnt(0)" ::: "memory")
#define NOVM ((void)0)

#define PHASE_F(buf, kh, STAGE, VME) do {                                     \
    const uint32_t Ar_ = abase + (buf) * 65536u + (kh) * 16384u;              \
    const uint32_t Br_ = bbase + (buf) * 65536u + (kh) * 16384u;              \
    bf16x8 af0_, af1_, af2_, af3_;                                            \
    DSR(af0_, Ar_, 0);    DSR(af1_, Ar_, 1024);                               \
    DSR(af2_, Ar_, 2048); DSR(af3_, Ar_, 3072);                               \
    DSR(bqf[0], Br_, 0);    DSR(bqf[1], Br_, 1024);                           \
    DSR(bqf[2], Br_, 2048); DSR(bqf[3], Br_, 3072);                           \
    STAGE;                                                                    \
    __builtin_amdgcn_s_barrier();                                             \
    asm volatile("s_waitcnt lgkmcnt(0)" ::: "memory");                        \
    __builtin_amdgcn_sched_barrier(0);                                        \
    __builtin_amdgcn_s_setprio(1);                                            \
    acc[0][0] = __builtin_amdgcn_mfma_f32_16x16x32_bf16(af0_, bqf[0], acc[0][0], 0, 0, 0); \
    acc[0][1] = __builtin_amdgcn_mfma_f32_16x16x32_bf16(af0_, bqf[1], acc[0][1], 0, 0, 0); \
    acc[0][2] = __builtin_amdgcn_mfma_f32_16x16x32_bf16(af0_, bqf[2], acc[0][2], 0, 0, 0); \
    acc[0][3] = __builtin_amdgcn_mfma_f32_16x16x32_bf16(af0_, bqf[3], acc[0][3], 0, 0, 0); \
    acc[1][0] = __builtin_amdgcn_mfma_f32_16x16x32_bf16(af1_, bqf[0], acc[1][0], 0, 0, 0); \
    acc[1][1] = __builtin_amdgcn_mfma_f32_16x16x32_bf16(af1_, bqf[1], acc[1][1], 0, 0, 0); \
    acc[1][2] = __builtin_amdgcn_mfma_f32_16x16x32_bf16(af1_, bqf[2], acc[1][2], 0, 0, 0); \
    acc[1][3] = __builtin_amdgcn_mfma_f32_16x16x32_bf16(af1_, bqf[3], acc[1][3], 0, 0, 0); \
    acc[2][0] = __builtin_amdgcn_mfma_f32_16x16x32_bf16(af2_, bqf[0], acc[2][0], 0, 0, 0); \
    acc[2][1] = __builtin_amdgcn_mfma_f32_16x16x32_bf16(af2_, bqf[1], acc[2][1], 0, 0, 0); \
    acc[2][2] = __builtin_amdgcn_mfma_f32_16x16x32_bf16(af2_, bqf[2], acc[2][2], 0, 0, 0); \
    acc[2][3] = __builtin_amdgcn_mfma_f32_16x16x32_bf16(af2_, bqf[3], acc[2][3], 0, 0, 0); \
    acc[3][0] = __builtin_amdgcn_mfma_f32_16x16x32_bf16(af3_, bqf[0], acc[3][0], 0, 0, 0); \
    acc[3][1] = __builtin_amdgcn_mfma_f32_16x16x32_bf16(af3_, bqf[1], acc[3][1], 0, 0, 0); \
    acc[3][2] = __builtin_amdgcn_mfma_f32_16x16x32_bf16(af3_, bqf[2], acc[3][2], 0, 0, 0); \
    acc[3][3] = __builtin_amdgcn_mfma_f32_16x16x32_bf16(af3_, bqf[3], acc[3][3], 0, 0, 0); \
    __builtin_amdgcn_s_setprio(0);                                            \
    VME;                                                                      \
    __builtin_amdgcn_s_barrier();                                             \
  } while (0)

#define PHASE_R(buf, kh, STAGE, VME) do {                                     \
    const uint32_t Ar_ = abase + (buf) * 65536u + (kh) * 16384u + 4096u;      \
    bf16x8 af0_, af1_, af2_, af3_;                                            \
    DSR(af0_, Ar_, 0);    DSR(af1_, Ar_, 1024);                               \
    DSR(af2_, Ar_, 2048); DSR(af3_, Ar_, 3072);                               \
    STAGE;                                                                    \
    __builtin_amdgcn_s_barrier();                                             \
    asm volatile("s_waitcnt lgkmcnt(0)" ::: "memory");                        \
    __builtin_amdgcn_sched_barrier(0);                                        \
    __builtin_amdgcn_s_setprio(1);                                            \
    acc[4][0] = __builtin_amdgcn_mfma_f32_16x16x32_bf16(af0_, bqf[0], acc[4][0], 0, 0, 0); \
    acc[4][1] = __builtin_amdgcn_mfma_f32_16x16x32_bf16(af0_, bqf[1], acc[4][1], 0, 0, 0); \
    acc[4][2] = __builtin_amdgcn_mfma_f32_16x16x32_bf16(af0_, bqf[2], acc[4][2], 0, 0, 0); \
    acc[4][3] = __builtin_amdgcn_mfma_f32_16x16x32_bf16(af0_, bqf[3], acc[4][3], 0, 0, 0); \
    acc[5][0] = __builtin_amdgcn_mfma_f32_16x16x32_bf16(af1_, bqf[0], acc[5][0], 0, 0, 0); \
    acc[5][1] = __builtin_amdgcn_mfma_f32_16x16x32_bf16(af1_, bqf[1], acc[5][1], 0, 0, 0); \
    acc[5][2] = __builtin_amdgcn_mfma_f32_16x16x32_bf16(af1_, bqf[2], acc[5][2], 0, 0, 0); \
    acc[5][3] = __builtin_amdgcn_mfma_f32_16x16x32_bf16(af1_, bqf[3], acc[5][3], 0, 0, 0); \
    acc[6][0] = __builtin_amdgcn_mfma_f32_16x16x32_bf16(af2_, bqf[0], acc[6][0], 0, 0, 0); \
    acc[6][1] = __builtin_amdgcn_mfma_f32_16x16x32_bf16(af2_, bqf[1], acc[6][1], 0, 0, 0); \
    acc[6][2] = __builtin_amdgcn_mfma_f32_16x16x32_bf16(af2_, bqf[2], acc[6][2], 0, 0, 0); \
    acc[6][3] = __builtin_amdgcn_mfma_f32_16x16x32_bf16(af2_, bqf[3], acc[6][3], 0, 0, 0); \
    acc[7][0] = __builtin_amdgcn_mfma_f32_16x16x32_bf16(af3_, bqf[0], acc[7][0], 0, 0, 0); \
    acc[7][1] = __builtin_amdgcn_mfma_f32_16x16x32_bf16(af3_, bqf[1], acc[7][1], 0, 0, 0); \
    acc[7][2] = __builtin_amdgcn_mfma_f32_16x16x32_bf16(af3_, bqf[2], acc[7][2], 0, 0, 0); \
    acc[7][3] = __builtin_amdgcn_mfma_f32_16x16x32_bf16(af3_, bqf[3], acc[7][3], 0, 0, 0); \
    __builtin_amdgcn_s_setprio(0);                                            \
    VME;                                                                      \
    __builtin_amdgcn_s_barrier();                                             \
  } while (0)

  // prologue: tile0 (4 stages, 8 loads); drain its kh0 A+B (oldest 4 loads)
  STAGE_A(0, 0, 0); STAGE_B(0, 0, 0); STAGE_A(0, 1, 0); STAGE_B(0, 1, 0);
  asm volatile("s_waitcnt vmcnt(4)" ::: "memory");
  __builtin_amdgcn_s_barrier();

  for (int t = 0; t < 7; ++t) {
    const int j1 = 2 * t + 1, j2 = 2 * t + 2;
    PHASE_F(0, 0, STAGE_A(1, 0, j1), NOVM);
    PHASE_R(0, 0, STAGE_B(1, 0, j1), VM4);
    PHASE_F(0, 1, STAGE_A(1, 1, j1), NOVM);
    PHASE_R(0, 1, STAGE_B(1, 1, j1), VM4);
    PHASE_F(1, 0, STAGE_A(0, 0, j2), NOVM);
    PHASE_R(1, 0, STAGE_B(0, 0, j2), VM4);
    PHASE_F(1, 1, STAGE_A(0, 1, j2), NOVM);
    PHASE_R(1, 1, STAGE_B(0, 1, j2), VM4);
  }
  // tail: tiles 14,15; only tile15 still needs staging
  PHASE_F(0, 0, STAGE_A(1, 0, 15), NOVM);
  PHASE_R(0, 0, STAGE_B(1, 0, 15), VM4);
  PHASE_F(0, 1, STAGE_A(1, 1, 15), NOVM);
  PHASE_R(0, 1, STAGE_B(1, 1, 15), VM4);
  PHASE_F(1, 0, NOSTAGE, NOVM);
  PHASE_R(1, 0, NOSTAGE, VM0);
  PHASE_F(1, 1, NOSTAGE, NOVM);
  PHASE_R(1, 1, NOSTAGE, NOVM);

#undef PHASE_F
#undef PHASE_R
#undef STAGE_A
#undef STAGE_B
#undef DSR

  const int seg = n0 >> 10;                      // block-uniform: 0=Q 1=K 2=V
  const float* bias = (seg == 0) ? bq : (seg == 1) ? bk : bvv;
  bf16_t* QK = (seg == 0) ? Qh : Kh;
#pragma unroll
  for (int mi = 0; mi < 8; ++mi) {
    const int rbase = m0 + wr * 128 + mi * 16 + g4 * 4;
    const int b = rbase >> 9, pb = rbase & 511;
#pragma unroll
    for (int nj = 0; nj < 4; ++nj) {
      const int col = n0 + wc * 64 + nj * 16 + ln15;
      const int cl = col & 1023;
      const int h = cl >> 6, hd = cl & 63;
      const float bv = bias[cl];
      if (seg < 2) {
        // head-major: [b][h][p][hd]
#pragma unroll
        for (int r = 0; r < 4; ++r)
          QK[(((size_t)(b * cH + h)) * cP + pb + r) * cHD + hd] =
              (bf16_t)(acc[mi][nj][r] + bv);
      } else {
        bf16x4 pk;
#pragma unroll
        for (int r = 0; r < 4; ++r) pk[r] = (bf16_t)(acc[mi][nj][r] + bv);
        *(bf16x4*)(Vt + ((size_t)((b * cH + h) * cHD + hd)) * cVTP + 128 + pb) = pk;
      }
    }
  }
}

// Output-projection GEMM (fp32 out), 128x128 tile + XCD swizzle
__global__ __launch_bounds__(256)
void gemm_bt_k(const bf16_t* __restrict__ A, const bf16_t* __restrict__ Bt,
               const float* __restrict__ bias, float* __restrict__ C,
               int M, int N, int K) {
  __shared__ __align__(16) bf16_t As[2][128 * 32];
  __shared__ __align__(16) bf16_t Bs[2][128 * 32];
  const int tid = threadIdx.x;
  const int wv = tid >> 6, ln = tid & 63;
  const int ln15 = ln & 15, g4 = ln >> 4;

  const int g = blockIdx.x + 8 * blockIdx.y;    // [0, 2048)
  const int xcd = g & 7, s = g >> 3;            // s in [0, 256)
  const int nb = s & 7, mloc = s >> 3;          // mloc in [0, 32)
  const int m0 = (xcd * 32 + mloc) * 128, n0 = nb * 128;

  const int wm = (wv >> 1) * 64, wn = (wv & 1) * 64;
  const bf16_t* Ab = A + (size_t)m0 * K;
  const bf16_t* Bb = Bt + (size_t)n0 * K;

  auto stage = [&](const bf16_t* G, bf16_t* L, int k0) {
#pragma unroll
    for (int gg = 0; gg < 2; ++gg) {
      int slot = gg * 256 + tid;
      gld_lds16(G + (size_t)(slot >> 2) * K + (k0 + (slot & 3) * 8), L + slot * 8);
    }
  };

  f32x4 acc[4][4];
#pragma unroll
  for (int i = 0; i < 4; ++i)
#pragma unroll
    for (int j = 0; j < 4; ++j) acc[i][j] = {0.f, 0.f, 0.f, 0.f};

  const int nk = K >> 5;
  stage(Ab, As[0], 0);
  stage(Bb, Bs[0], 0);
  for (int kt = 0; kt < nk; ++kt) {
    __syncthreads();
    if (kt + 1 < nk) {
      stage(Ab, As[(kt + 1) & 1], (kt + 1) * 32);
      stage(Bb, Bs[(kt + 1) & 1], (kt + 1) * 32);
    }
    const bf16_t* Asb = As[kt & 1];
    const bf16_t* Bsb = Bs[kt & 1];
    bf16x8 af[4], bfr[4];
#pragma unroll
    for (int i = 0; i < 4; ++i)
      af[i] = *(const bf16x8*)(Asb + (wm + i * 16 + ln15) * 32 + g4 * 8);
#pragma unroll
    for (int j = 0; j < 4; ++j)
      bfr[j] = *(const bf16x8*)(Bsb + (wn + j * 16 + ln15) * 32 + g4 * 8);
#pragma unroll
    for (int i = 0; i < 4; ++i)
#pragma unroll
      for (int j = 0; j < 4; ++j)
        acc[i][j] = __builtin_amdgcn_mfma_f32_16x16x32_bf16(af[i], bfr[j], acc[i][j], 0, 0, 0);
  }

#pragma unroll
  for (int i = 0; i < 4; ++i) {
    const int rbase = m0 + wm + i * 16 + g4 * 4;
#pragma unroll
    for (int j = 0; j < 4; ++j) {
      const int col = n0 + wn + j * 16 + ln15;
      const float bv = bias[col];
#pragma unroll
      for (int r = 0; r < 4; ++r)
        C[(size_t)(rbase + r) * N + col] = acc[i][j][r] + bv;
    }
  }
}

// ---------------------------------------------------------------------------
// Windowed attention v3: block = (head, batch, t-chunk); 4 waves each own a
// 16-token tile; 2 iterations cover the 128-token chunk. Q/K head-major.
__global__ __launch_bounds__(256)
void attn3_k(const bf16_t* __restrict__ Q, const bf16_t* __restrict__ Kv,
             const bf16_t* __restrict__ Vt, const int* __restrict__ rr,
             bf16_t* __restrict__ O) {
  __shared__ __align__(16) bf16_t Pl[4][16][168];
  const int tid = threadIdx.x;
  const int wv = tid >> 6, ln = tid & 63, ln15 = ln & 15, g4 = ln >> 4;
  const int h = blockIdx.x, b = blockIdx.y, tc = blockIdx.z;
  bf16_t(*Pw)[168] = Pl[wv];
  const bf16_t* vb = Vt + ((size_t)(b * cH + h)) * cHD * cVTP;
  const bf16_t* qb = Q + ((size_t)(b * cH + h)) * cP * cHD;
  const bf16_t* kb = Kv + ((size_t)(b * cH + h)) * cP * cHD;

  for (int sub = 0; sub < 2; ++sub) {
    const int t0 = (tc * 2 + sub) * 64 + wv * 16;
    const int sbase = t0 - 128;

    int rv[4];
#pragma unroll
    for (int r = 0; r < 4; ++r) rv[r] = rr[b * cP + t0 + g4 * 4 + r];

    // Q A-frag: m = ln15 (t), k = g4*8+j (hd)
    const bf16_t* qp = qb + (size_t)(t0 + ln15) * cHD + g4 * 8;
    const bf16x8 qa0 = *(const bf16x8*)qp;
    const bf16x8 qa1 = *(const bf16x8*)(qp + 32);

    // QK^T over 9 s-chunks of 16 (s in [t0-128, t0+15])
    f32x4 lg[9];
#pragma unroll
    for (int c = 0; c < 9; ++c) {
      const int s = sbase + c * 16 + ln15;  // B-frag n = ln15 (s), k = hd
      bf16x8 k0v, k1v;
      if ((unsigned)s < (unsigned)cP) {
        const bf16_t* kp = kb + (size_t)s * cHD + g4 * 8;
        k0v = *(const bf16x8*)kp;
        k1v = *(const bf16x8*)(kp + 32);
      } else {
#pragma unroll
        for (int z = 0; z < 8; ++z) { k0v[z] = (bf16_t)0.f; k1v[z] = (bf16_t)0.f; }
      }
      f32x4 a = {0.f, 0.f, 0.f, 0.f};
      a = __builtin_amdgcn_mfma_f32_16x16x32_bf16(qa0, k0v, a, 0, 0, 0);
      a = __builtin_amdgcn_mfma_f32_16x16x32_bf16(qa1, k1v, a, 0, 0, 0);
      lg[c] = a;
    }

    // mask + scale; C layout: col(s)=ln15, row(t)=g4*4+reg
    float mx[4] = {-1e30f, -1e30f, -1e30f, -1e30f};
#pragma unroll
    for (int c = 0; c < 9; ++c)
#pragma unroll
      for (int r = 0; r < 4; ++r) {
        const int s = sbase + c * 16 + ln15;
        const int t = t0 + g4 * 4 + r;
        const bool ok = (s >= rv[r]) && (s <= t) && (t - s < cW);
        const float l = ok ? lg[c][r] * cSCALE : -1e30f;
        lg[c][r] = l;
        mx[r] = fmaxf(mx[r], l);
      }
#pragma unroll
    for (int r = 0; r < 4; ++r) {
      mx[r] = fmaxf(mx[r], __shfl_xor(mx[r], 1));
      mx[r] = fmaxf(mx[r], __shfl_xor(mx[r], 2));
      mx[r] = fmaxf(mx[r], __shfl_xor(mx[r], 4));
      mx[r] = fmaxf(mx[r], __shfl_xor(mx[r], 8));
    }
    float sm[4] = {0.f, 0.f, 0.f, 0.f};
#pragma unroll
    for (int c = 0; c < 9; ++c)
#pragma unroll
      for (int r = 0; r < 4; ++r) {
        const float e = __expf(lg[c][r] - mx[r]);
        lg[c][r] = e;
        sm[r] += e;
      }
#pragma unroll
    for (int r = 0; r < 4; ++r) {
      sm[r] += __shfl_xor(sm[r], 1);
      sm[r] += __shfl_xor(sm[r], 2);
      sm[r] += __shfl_xor(sm[r], 4);
      sm[r] += __shfl_xor(sm[r], 8);
    }
    float inv[4];
#pragma unroll
    for (int r = 0; r < 4; ++r) inv[r] = 1.f / sm[r];

    // P -> LDS (C-layout write), zero pad cols 144..159 for the 5th PV chunk
#pragma unroll
    for (int c = 0; c < 9; ++c)
#pragma unroll
      for (int r = 0; r < 4; ++r)
        Pw[g4 * 4 + r][c * 16 + ln15] = (bf16_t)(lg[c][r] * inv[r]);
#pragma unroll
    for (int z = 0; z < 4; ++z)
      Pw[ln15][144 + g4 * 4 + z] = (bf16_t)0.f;

    // PV: A = P (m=t, k=s from LDS), B = Vt rows (n=hd, k=s contiguous)
    f32x4 oacc[4];
#pragma unroll
    for (int j = 0; j < 4; ++j) oacc[j] = {0.f, 0.f, 0.f, 0.f};
#pragma unroll
    for (int c2 = 0; c2 < 5; ++c2) {
      const bf16x8 pa = *(const bf16x8*)(&Pw[ln15][c2 * 32 + g4 * 8]);
#pragma unroll
      for (int j = 0; j < 4; ++j) {
        const bf16x8 vf =
            *(const bf16x8*)(vb + (size_t)(j * 16 + ln15) * cVTP + (t0 + c2 * 32 + g4 * 8));
        oacc[j] = __builtin_amdgcn_mfma_f32_16x16x32_bf16(pa, vf, oacc[j], 0, 0, 0);
      }
    }
#pragma unroll
    for (int j = 0; j < 4; ++j) {
      const int col = h * cHD + j * 16 + ln15;
#pragma unroll
      for (int r = 0; r < 4; ++r)
        O[((size_t)(b * cP + t0 + g4 * 4 + r)) * cDWM + col] = (bf16_t)oacc[j][r];
    }
  }
}

// ---------------------------------------------------------------------------
extern "C" void kernel_launch(void* const* d_in, const int* in_sizes, int n_in,
                              void* d_out, int out_size, void* d_ws, size_t ws_size,
                              hipStream_t stream) {
  (void)in_sizes; (void)n_in; (void)out_size; (void)ws_size;
  const float* x  = (const float*)d_in[0];
  const int* mask = (const int*)d_in[1];
  const float* Wq = (const float*)d_in[2];
  const float* bq = (const float*)d_in[3];
  const float* Wk = (const float*)d_in[4];
  const float* bk = (const float*)d_in[5];
  const float* Wv = (const float*)d_in[6];
  const float* bv = (const float*)d_in[7];
  const float* Wo = (const float*)d_in[8];
  const float* bo = (const float*)d_in[9];
  float* out = (float*)d_out;

  char* ws = (char*)d_ws;
  size_t off = 0;
  bf16_t* Xbf = (bf16_t*)(ws + off); off += (size_t)cM * cD * 2;          // 64 MiB
  bf16_t* Wqt = (bf16_t*)(ws + off); off += (size_t)cD * cDWM * 2;        // contiguous
  bf16_t* Wkt = (bf16_t*)(ws + off); off += (size_t)cD * cDWM * 2;        //   [3072][1024]
  bf16_t* Wvt = (bf16_t*)(ws + off); off += (size_t)cD * cDWM * 2;        //   QKV block
  bf16_t* Wot = (bf16_t*)(ws + off); off += (size_t)cDWM * cD * 2;
  bf16_t* Qh  = (bf16_t*)(ws + off); off += (size_t)cM * cDWM * 2;        // 64 MiB
  bf16_t* Kh  = (bf16_t*)(ws + off); off += (size_t)cM * cDWM * 2;        // 64 MiB
  bf16_t* Vt  = (bf16_t*)(ws + off); off += (size_t)cBS * cH * cHD * cVTP * 2;  // 84 MiB
  int* rbuf   = (int*)(ws + off);    off += (size_t)cBS * cP * 4;
  bf16_t* Ob  = Xbf;  // X no longer needed after the QKV projection

  cvt_x_k<<<(cM * cD / 4 + 255) / 256, 256, 0, stream>>>(x, Xbf, cM * cD);
  cvt_wt_k<<<dim3(32, 32, 4), 256, 0, stream>>>(Wq, Wk, Wv, Wo, Wqt, Wkt, Wvt, Wot);
  resets2_k<<<cBS, cP, 0, stream>>>(mask, rbuf);

  gemm_qkv8_k<<<dim3(12, 128), 512, 0, stream>>>(Xbf, Wqt, bq, bk, bv, Qh, Kh, Vt);

  attn3_k<<<dim3(cH, cBS, 4), 256, 0, stream>>>(Qh, Kh, Vt, rbuf, Ob);

  gemm_bt_k<<<dim3(8, 256), 256, 0, stream>>>(Ob, Wot, bo, out, cM, cD, cDWM);
}

// Round 6
// 544.401 us; speedup vs baseline: 1.7505x; 1.0041x over previous
//
#include <hip/hip_runtime.h>
#include <stdint.h>

typedef __bf16 bf16_t;
typedef __bf16 bf16x8 __attribute__((ext_vector_type(8)));
typedef __bf16 bf16x4 __attribute__((ext_vector_type(4)));
typedef float  f32x4  __attribute__((ext_vector_type(4)));

constexpr int cBS = 64, cP = 512, cD = 1024, cDWM = 1024, cH = 16, cHD = 64, cW = 128;
constexpr int cVTP = 672;           // padded p-extent of Vt (sp = p + 128, max used 656)
constexpr int cM = cBS * cP;        // 32768
constexpr float cSCALE = 0.125f;    // 1/sqrt(64)

__device__ __forceinline__ void gld_lds16(const void* g, void* l) {
#if __has_builtin(__builtin_amdgcn_global_load_lds)
  __builtin_amdgcn_global_load_lds(
      (__attribute__((address_space(1))) void*)g,
      (__attribute__((address_space(3))) void*)l, 16, 0, 0);
#else
  *(bf16x8*)l = *(const bf16x8*)g;
#endif
}

// ---------------------------------------------------------------------------
// fp32 -> bf16 conversion of X
__global__ void cvt_x_k(const float* __restrict__ X, bf16_t* __restrict__ Y, int n) {
  int i = (blockIdx.x * blockDim.x + threadIdx.x) * 4;
  if (i >= n) return;
  float4 v = *(const float4*)(X + i);
  bf16x4 o;
  o[0] = (bf16_t)v.x; o[1] = (bf16_t)v.y; o[2] = (bf16_t)v.z; o[3] = (bf16_t)v.w;
  *(bf16x4*)(Y + i) = o;
}

// transpose + convert the four 1024x1024 weights: W[k][n] fp32 -> Wt[n][k] bf16
__global__ void cvt_wt_k(const float* __restrict__ W0, const float* __restrict__ W1,
                         const float* __restrict__ W2, const float* __restrict__ W3,
                         bf16_t* __restrict__ T0, bf16_t* __restrict__ T1,
                         bf16_t* __restrict__ T2, bf16_t* __restrict__ T3) {
  __shared__ float tile[32][33];
  const float* Wsrc; bf16_t* Tdst;
  switch (blockIdx.z) {
    case 0: Wsrc = W0; Tdst = T0; break;
    case 1: Wsrc = W1; Tdst = T1; break;
    case 2: Wsrc = W2; Tdst = T2; break;
    default: Wsrc = W3; Tdst = T3; break;
  }
  const int n0 = blockIdx.x * 32, k0 = blockIdx.y * 32;
  const int c = threadIdx.x & 31, r8 = threadIdx.x >> 5;
#pragma unroll
  for (int q = 0; q < 4; ++q) {
    int row = r8 + q * 8;
    tile[row][c] = Wsrc[(size_t)(k0 + row) * 1024 + n0 + c];
  }
  __syncthreads();
#pragma unroll
  for (int q = 0; q < 4; ++q) {
    int row = r8 + q * 8;
    Tdst[(size_t)(n0 + row) * 1024 + k0 + c] = (bf16_t)tile[c][row];
  }
}

// r[b][t] = index of last reset at-or-before t (0 if none): parallel max-scan
__global__ void resets2_k(const int* __restrict__ mask, int* __restrict__ r) {
  __shared__ int sm[cP];
  const int b = blockIdx.x, t = threadIdx.x;
  sm[t] = mask[b * cP + t] ? t : 0;
  __syncthreads();
#pragma unroll
  for (int d = 1; d < cP; d <<= 1) {
    int u = (t >= d) ? sm[t - d] : 0;
    __syncthreads();
    if (u > sm[t]) sm[t] = u;
    __syncthreads();
  }
  r[b * cP + t] = sm[t];
}

// ---------------------------------------------------------------------------
// Fused QKV GEMM, 256x256 tile, MERGED 4-phase pipeline (was 8-phase).
// C[M][3072] = A[M][1024] * Wt[3072][1024]^T.
// Seg 0 -> Q head-major [b][h][p][hd], 1 -> K head-major, 2 -> Vt [b][h][hd][sp].
//
// Rationale (R0/R2/R4 data): phase time pinned ~1580 cyc regardless of LDS
// conflicts/read-count/asm-reads; MFMA floor 621 cyc -> ~950 cyc/phase is
// per-phase FIXED overhead (barriers, lgkm drain, wave resync). Halving the
// phase count at constant MFMA work amortizes it: one phase per (buf,kh)
// region = 12 ds_read_b128 (8 A + 4 B), one full-region stage (4 gld_lds),
// 32 MFMA, one counted VM4, 2 barriers.
//
// LDS (128 KiB): per dbuf (64 KiB): A kh0 [0,16K) | A kh1 [16K,32K) |
//                                   B kh0 [32K,48K) | B kh1 [48K,64K)
// Each 16 KiB region: 256 rows x 32 bf16 in FRAGMENT ORDER (16 subtiles of
// 16 rows; element (row r, 16B k-chunk c) at subtile*1024 + (c*16+(r&15))*16)
// -> a wave's frag read covers 1024 consecutive bytes: 0 bank conflicts
// (verified R2). global_load_lds dest stays linear (tid*16); the GLOBAL
// source is permuted to match (rule #21).
//
// Schedule per iteration (tiles j0=2t -> buf0, j1=2t+1 -> buf1):
//  A1 (0,kh0): stage full region (1,kh0,j1);  VM4
//  A2 (0,kh1): stage (1,kh1,j1);              VM4
//  A3 (1,kh0): stage (0,kh0,j2);              VM4
//  A4 (1,kh1): stage (0,kh1,j2);              VM4
// Each VM4 (end of phase) keeps exactly this phase's 4 staged loads and
// drains the 4 older ones = the region read next phase, which was issued
// 2 phases (~4400 cyc) earlier -> latency covered, never drains to 0.
__global__ __launch_bounds__(512, 2)
void gemm_qkv8_k(const bf16_t* __restrict__ A, const bf16_t* __restrict__ Wt,
                 const float* __restrict__ bq, const float* __restrict__ bk,
                 const float* __restrict__ bvv,
                 bf16_t* __restrict__ Qh, bf16_t* __restrict__ Kh,
                 bf16_t* __restrict__ Vt) {
  __shared__ __align__(16) char LDS[131072];
  const int tid = threadIdx.x;
  const int wid = tid >> 6, ln = tid & 63;
  const int ln15 = ln & 15, g4 = ln >> 4;
  const int wr = wid >> 2, wc = wid & 3;   // wave -> (row half, col quarter)

  // XCD swizzle: per-XCD m-slice, n-fastest so the A-panel stays L2-resident
  const int g = blockIdx.x + 12 * blockIdx.y;   // [0, 1536)
  const int xcd = g & 7, s = g >> 3;            // s in [0, 192)
  const int nb = s % 12, mloc = s / 12;         // mloc in [0, 16)
  const int m0 = (xcd * 16 + mloc) * 256, n0 = nb * 256;

  const bf16_t* Ab = A + (size_t)m0 * 1024;
  const bf16_t* Bb = Wt + (size_t)n0 * 1024;

  // staging: thread covers LDS chunks q = tid and q+512 of a 16 KiB region.
  // q -> subtile q>>6, row-in-subtile q&15, k-chunk (q>>4)&3
  // global element = ((q>>6)*16 + (q&15))*1024 + ((q>>4)&3)*8 (+128 rows @ +512)
  const int srow = (tid >> 6) * 16 + (tid & 15);    // 0..127
  const int kc = (tid >> 4) & 3;
  const size_t aoff = (size_t)srow * 1024 + (size_t)(kc * 8);
  char* const lbase = LDS + tid * 16;

  // frag read lane addressing: 1024 consecutive bytes per subtile
  const int lane16 = (g4 * 16 + ln15) * 16;
  const int abase = (wr * 8) * 1024 + lane16;   // + mi*1024, mi = 0..7
  const int bbase = (wc * 4) * 1024 + lane16;   // + nj*1024, within B region

  f32x4 acc[8][4];
#pragma unroll
  for (int i = 0; i < 8; ++i)
#pragma unroll
    for (int j = 0; j < 4; ++j) acc[i][j] = {0.f, 0.f, 0.f, 0.f};

#define STAGE_A(buf, kh, j) do {                                              \
    const bf16_t* gp_ = Ab + (size_t)((j) * 64 + (kh) * 32) + aoff;           \
    char* lp_ = lbase + (buf) * 65536 + (kh) * 16384;                         \
    gld_lds16(gp_, lp_);                                                      \
    gld_lds16(gp_ + (size_t)128 * 1024, lp_ + 8192);                          \
  } while (0)

#define STAGE_B(buf, kh, j) do {                                              \
    const bf16_t* gp_ = Bb + (size_t)((j) * 64 + (kh) * 32) + aoff;           \
    char* lp_ = lbase + (buf) * 65536 + (kh) * 16384 + 32768;                 \
    gld_lds16(gp_, lp_);                                                      \
    gld_lds16(gp_ + (size_t)128 * 1024, lp_ + 8192);                          \
  } while (0)

#define NOSTAGE ((void)0)
#define VM4 asm volatile("s_waitcnt vmcnt(4)" ::: "memory")
#define VM0 asm volatile("s_waitcnt vmcnt(0)" ::: "memory")
#define NOVM ((void)0)

// One merged phase: read all 12 frags of region (buf,kh), issue the stage,
// barrier, drain LDS, 32 MFMA, counted vmcnt, barrier.
#define PHASE(buf, kh, STAGE, VME) do {                                       \
    const char* Ar_ = LDS + (buf) * 65536 + (kh) * 16384 + abase;             \
    const char* Br_ = LDS + (buf) * 65536 + (kh) * 16384 + 32768 + bbase;     \
    bf16x8 af_[8], bf_[4];                                                    \
    _Pragma("unroll")                                                         \
    for (int mi_ = 0; mi_ < 8; ++mi_)                                         \
      af_[mi_] = *(const bf16x8*)(Ar_ + mi_ * 1024);                          \
    _Pragma("unroll")                                                         \
    for (int nj_ = 0; nj_ < 4; ++nj_)                                         \
      bf_[nj_] = *(const bf16x8*)(Br_ + nj_ * 1024);                          \
    STAGE;                                                                    \
    __builtin_amdgcn_s_barrier();                                             \
    asm volatile("s_waitcnt lgkmcnt(0)" ::: "memory");                        \
    __builtin_amdgcn_s_setprio(1);                                            \
    _Pragma("unroll")                                                         \
    for (int mi_ = 0; mi_ < 8; ++mi_)                                         \
      _Pragma("unroll")                                                       \
      for (int nj_ = 0; nj_ < 4; ++nj_)                                       \
        acc[mi_][nj_] = __builtin_amdgcn_mfma_f32_16x16x32_bf16(              \
            af_[mi_], bf_[nj_], acc[mi_][nj_], 0, 0, 0);                      \
    __builtin_amdgcn_s_setprio(0);                                            \
    VME;                                                                      \
    __builtin_amdgcn_s_barrier();                                             \
  } while (0)

  // prologue: tile0 both regions (8 loads); drain kh0's 4 (keep kh1 in flight)
  STAGE_A(0, 0, 0); STAGE_B(0, 0, 0);
  STAGE_A(0, 1, 0); STAGE_B(0, 1, 0);
  VM4;
  __builtin_amdgcn_s_barrier();

  for (int t = 0; t < 7; ++t) {
    const int j1 = 2 * t + 1, j2 = 2 * t + 2;
    PHASE(0, 0, { STAGE_A(1, 0, j1); STAGE_B(1, 0, j1); }, VM4);
    PHASE(0, 1, { STAGE_A(1, 1, j1); STAGE_B(1, 1, j1); }, VM4);
    PHASE(1, 0, { STAGE_A(0, 0, j2); STAGE_B(0, 0, j2); }, VM4);
    PHASE(1, 1, { STAGE_A(0, 1, j2); STAGE_B(0, 1, j2); }, VM4);
  }
  // tail: tiles 14,15; only tile15 still needs staging
  PHASE(0, 0, { STAGE_A(1, 0, 15); STAGE_B(1, 0, 15); }, VM4);
  PHASE(0, 1, { STAGE_A(1, 1, 15); STAGE_B(1, 1, 15); }, VM4);
  PHASE(1, 0, NOSTAGE, VM0);
  PHASE(1, 1, NOSTAGE, NOVM);

#undef PHASE
#undef STAGE_A
#undef STAGE_B

  const int seg = n0 >> 10;                      // block-uniform: 0=Q 1=K 2=V
  const float* bias = (seg == 0) ? bq : (seg == 1) ? bk : bvv;
  bf16_t* QK = (seg == 0) ? Qh : Kh;
#pragma unroll
  for (int mi = 0; mi < 8; ++mi) {
    const int rbase = m0 + wr * 128 + mi * 16 + g4 * 4;
    const int b = rbase >> 9, pb = rbase & 511;
#pragma unroll
    for (int nj = 0; nj < 4; ++nj) {
      const int col = n0 + wc * 64 + nj * 16 + ln15;
      const int cl = col & 1023;
      const int h = cl >> 6, hd = cl & 63;
      const float bv = bias[cl];
      if (seg < 2) {
        // head-major: [b][h][p][hd]
#pragma unroll
        for (int r = 0; r < 4; ++r)
          QK[(((size_t)(b * cH + h)) * cP + pb + r) * cHD + hd] =
              (bf16_t)(acc[mi][nj][r] + bv);
      } else {
        bf16x4 pk;
#pragma unroll
        for (int r = 0; r < 4; ++r) pk[r] = (bf16_t)(acc[mi][nj][r] + bv);
        *(bf16x4*)(Vt + ((size_t)((b * cH + h) * cHD + hd)) * cVTP + 128 + pb) = pk;
      }
    }
  }
}

// Output-projection GEMM (fp32 out), 128x128 tile + XCD swizzle
__global__ __launch_bounds__(256)
void gemm_bt_k(const bf16_t* __restrict__ A, const bf16_t* __restrict__ Bt,
               const float* __restrict__ bias, float* __restrict__ C,
               int M, int N, int K) {
  __shared__ __align__(16) bf16_t As[2][128 * 32];
  __shared__ __align__(16) bf16_t Bs[2][128 * 32];
  const int tid = threadIdx.x;
  const int wv = tid >> 6, ln = tid & 63;
  const int ln15 = ln & 15, g4 = ln >> 4;

  const int g = blockIdx.x + 8 * blockIdx.y;    // [0, 2048)
  const int xcd = g & 7, s = g >> 3;            // s in [0, 256)
  const int nb = s & 7, mloc = s >> 3;          // mloc in [0, 32)
  const int m0 = (xcd * 32 + mloc) * 128, n0 = nb * 128;

  const int wm = (wv >> 1) * 64, wn = (wv & 1) * 64;
  const bf16_t* Ab = A + (size_t)m0 * K;
  const bf16_t* Bb = Bt + (size_t)n0 * K;

  auto stage = [&](const bf16_t* G, bf16_t* L, int k0) {
#pragma unroll
    for (int gg = 0; gg < 2; ++gg) {
      int slot = gg * 256 + tid;
      gld_lds16(G + (size_t)(slot >> 2) * K + (k0 + (slot & 3) * 8), L + slot * 8);
    }
  };

  f32x4 acc[4][4];
#pragma unroll
  for (int i = 0; i < 4; ++i)
#pragma unroll
    for (int j = 0; j < 4; ++j) acc[i][j] = {0.f, 0.f, 0.f, 0.f};

  const int nk = K >> 5;
  stage(Ab, As[0], 0);
  stage(Bb, Bs[0], 0);
  for (int kt = 0; kt < nk; ++kt) {
    __syncthreads();
    if (kt + 1 < nk) {
      stage(Ab, As[(kt + 1) & 1], (kt + 1) * 32);
      stage(Bb, Bs[(kt + 1) & 1], (kt + 1) * 32);
    }
    const bf16_t* Asb = As[kt & 1];
    const bf16_t* Bsb = Bs[kt & 1];
    bf16x8 af[4], bfr[4];
#pragma unroll
    for (int i = 0; i < 4; ++i)
      af[i] = *(const bf16x8*)(Asb + (wm + i * 16 + ln15) * 32 + g4 * 8);
#pragma unroll
    for (int j = 0; j < 4; ++j)
      bfr[j] = *(const bf16x8*)(Bsb + (wn + j * 16 + ln15) * 32 + g4 * 8);
#pragma unroll
    for (int i = 0; i < 4; ++i)
#pragma unroll
      for (int j = 0; j < 4; ++j)
        acc[i][j] = __builtin_amdgcn_mfma_f32_16x16x32_bf16(af[i], bfr[j], acc[i][j], 0, 0, 0);
  }

#pragma unroll
  for (int i = 0; i < 4; ++i) {
    const int rbase = m0 + wm + i * 16 + g4 * 4;
#pragma unroll
    for (int j = 0; j < 4; ++j) {
      const int col = n0 + wn + j * 16 + ln15;
      const float bv = bias[col];
#pragma unroll
      for (int r = 0; r < 4; ++r)
        C[(size_t)(rbase + r) * N + col] = acc[i][j][r] + bv;
    }
  }
}

// ---------------------------------------------------------------------------
// Windowed attention v3: block = (head, batch, t-chunk); 4 waves each own a
// 16-token tile; 2 iterations cover the 128-token chunk. Q/K head-major.
__global__ __launch_bounds__(256)
void attn3_k(const bf16_t* __restrict__ Q, const bf16_t* __restrict__ Kv,
             const bf16_t* __restrict__ Vt, const int* __restrict__ rr,
             bf16_t* __restrict__ O) {
  __shared__ __align__(16) bf16_t Pl[4][16][168];
  const int tid = threadIdx.x;
  const int wv = tid >> 6, ln = tid & 63, ln15 = ln & 15, g4 = ln >> 4;
  const int h = blockIdx.x, b = blockIdx.y, tc = blockIdx.z;
  bf16_t(*Pw)[168] = Pl[wv];
  const bf16_t* vb = Vt + ((size_t)(b * cH + h)) * cHD * cVTP;
  const bf16_t* qb = Q + ((size_t)(b * cH + h)) * cP * cHD;
  const bf16_t* kb = Kv + ((size_t)(b * cH + h)) * cP * cHD;

  for (int sub = 0; sub < 2; ++sub) {
    const int t0 = (tc * 2 + sub) * 64 + wv * 16;
    const int sbase = t0 - 128;

    int rv[4];
#pragma unroll
    for (int r = 0; r < 4; ++r) rv[r] = rr[b * cP + t0 + g4 * 4 + r];

    // Q A-frag: m = ln15 (t), k = g4*8+j (hd)
    const bf16_t* qp = qb + (size_t)(t0 + ln15) * cHD + g4 * 8;
    const bf16x8 qa0 = *(const bf16x8*)qp;
    const bf16x8 qa1 = *(const bf16x8*)(qp + 32);

    // QK^T over 9 s-chunks of 16 (s in [t0-128, t0+15])
    f32x4 lg[9];
#pragma unroll
    for (int c = 0; c < 9; ++c) {
      const int s = sbase + c * 16 + ln15;  // B-frag n = ln15 (s), k = hd
      bf16x8 k0v, k1v;
      if ((unsigned)s < (unsigned)cP) {
        const bf16_t* kp = kb + (size_t)s * cHD + g4 * 8;
        k0v = *(const bf16x8*)kp;
        k1v = *(const bf16x8*)(kp + 32);
      } else {
#pragma unroll
        for (int z = 0; z < 8; ++z) { k0v[z] = (bf16_t)0.f; k1v[z] = (bf16_t)0.f; }
      }
      f32x4 a = {0.f, 0.f, 0.f, 0.f};
      a = __builtin_amdgcn_mfma_f32_16x16x32_bf16(qa0, k0v, a, 0, 0, 0);
      a = __builtin_amdgcn_mfma_f32_16x16x32_bf16(qa1, k1v, a, 0, 0, 0);
      lg[c] = a;
    }

    // mask + scale; C layout: col(s)=ln15, row(t)=g4*4+reg
    float mx[4] = {-1e30f, -1e30f, -1e30f, -1e30f};
#pragma unroll
    for (int c = 0; c < 9; ++c)
#pragma unroll
      for (int r = 0; r < 4; ++r) {
        const int s = sbase + c * 16 + ln15;
        const int t = t0 + g4 * 4 + r;
        const bool ok = (s >= rv[r]) && (s <= t) && (t - s < cW);
        const float l = ok ? lg[c][r] * cSCALE : -1e30f;
        lg[c][r] = l;
        mx[r] = fmaxf(mx[r], l);
      }
#pragma unroll
    for (int r = 0; r < 4; ++r) {
      mx[r] = fmaxf(mx[r], __shfl_xor(mx[r], 1));
      mx[r] = fmaxf(mx[r], __shfl_xor(mx[r], 2));
      mx[r] = fmaxf(mx[r], __shfl_xor(mx[r], 4));
      mx[r] = fmaxf(mx[r], __shfl_xor(mx[r], 8));
    }
    float sm[4] = {0.f, 0.f, 0.f, 0.f};
#pragma unroll
    for (int c = 0; c < 9; ++c)
#pragma unroll
      for (int r = 0; r < 4; ++r) {
        const float e = __expf(lg[c][r] - mx[r]);
        lg[c][r] = e;
        sm[r] += e;
      }
#pragma unroll
    for (int r = 0; r < 4; ++r) {
      sm[r] += __shfl_xor(sm[r], 1);
      sm[r] += __shfl_xor(sm[r], 2);
      sm[r] += __shfl_xor(sm[r], 4);
      sm[r] += __shfl_xor(sm[r], 8);
    }
    float inv[4];
#pragma unroll
    for (int r = 0; r < 4; ++r) inv[r] = 1.f / sm[r];

    // P -> LDS (C-layout write), zero pad cols 144..159 for the 5th PV chunk
#pragma unroll
    for (int c = 0; c < 9; ++c)
#pragma unroll
      for (int r = 0; r < 4; ++r)
        Pw[g4 * 4 + r][c * 16 + ln15] = (bf16_t)(lg[c][r] * inv[r]);
#pragma unroll
    for (int z = 0; z < 4; ++z)
      Pw[ln15][144 + g4 * 4 + z] = (bf16_t)0.f;

    // PV: A = P (m=t, k=s from LDS), B = Vt rows (n=hd, k=s contiguous)
    f32x4 oacc[4];
#pragma unroll
    for (int j = 0; j < 4; ++j) oacc[j] = {0.f, 0.f, 0.f, 0.f};
#pragma unroll
    for (int c2 = 0; c2 < 5; ++c2) {
      const bf16x8 pa = *(const bf16x8*)(&Pw[ln15][c2 * 32 + g4 * 8]);
#pragma unroll
      for (int j = 0; j < 4; ++j) {
        const bf16x8 vf =
            *(const bf16x8*)(vb + (size_t)(j * 16 + ln15) * cVTP + (t0 + c2 * 32 + g4 * 8));
        oacc[j] = __builtin_amdgcn_mfma_f32_16x16x32_bf16(pa, vf, oacc[j], 0, 0, 0);
      }
    }
#pragma unroll
    for (int j = 0; j < 4; ++j) {
      const int col = h * cHD + j * 16 + ln15;
#pragma unroll
      for (int r = 0; r < 4; ++r)
        O[((size_t)(b * cP + t0 + g4 * 4 + r)) * cDWM + col] = (bf16_t)oacc[j][r];
    }
  }
}

// ---------------------------------------------------------------------------
extern "C" void kernel_launch(void* const* d_in, const int* in_sizes, int n_in,
                              void* d_out, int out_size, void* d_ws, size_t ws_size,
                              hipStream_t stream) {
  (void)in_sizes; (void)n_in; (void)out_size; (void)ws_size;
  const float* x  = (const float*)d_in[0];
  const int* mask = (const int*)d_in[1];
  const float* Wq = (const float*)d_in[2];
  const float* bq = (const float*)d_in[3];
  const float* Wk = (const float*)d_in[4];
  const float* bk = (const float*)d_in[5];
  const float* Wv = (const float*)d_in[6];
  const float* bv = (const float*)d_in[7];
  const float* Wo = (const float*)d_in[8];
  const float* bo = (const float*)d_in[9];
  float* out = (float*)d_out;

  char* ws = (char*)d_ws;
  size_t off = 0;
  bf16_t* Xbf = (bf16_t*)(ws + off); off += (size_t)cM * cD * 2;          // 64 MiB
  bf16_t* Wqt = (bf16_t*)(ws + off); off += (size_t)cD * cDWM * 2;        // contiguous
  bf16_t* Wkt = (bf16_t*)(ws + off); off += (size_t)cD * cDWM * 2;        //   [3072][1024]
  bf16_t* Wvt = (bf16_t*)(ws + off); off += (size_t)cD * cDWM * 2;        //   QKV block
  bf16_t* Wot = (bf16_t*)(ws + off); off += (size_t)cDWM * cD * 2;
  bf16_t* Qh  = (bf16_t*)(ws + off); off += (size_t)cM * cDWM * 2;        // 64 MiB
  bf16_t* Kh  = (bf16_t*)(ws + off); off += (size_t)cM * cDWM * 2;        // 64 MiB
  bf16_t* Vt  = (bf16_t*)(ws + off); off += (size_t)cBS * cH * cHD * cVTP * 2;  // 84 MiB
  int* rbuf   = (int*)(ws + off);    off += (size_t)cBS * cP * 4;
  bf16_t* Ob  = Xbf;  // X no longer needed after the QKV projection

  cvt_x_k<<<(cM * cD / 4 + 255) / 256, 256, 0, stream>>>(x, Xbf, cM * cD);
  cvt_wt_k<<<dim3(32, 32, 4), 256, 0, stream>>>(Wq, Wk, Wv, Wo, Wqt, Wkt, Wvt, Wot);
  resets2_k<<<cBS, cP, 0, stream>>>(mask, rbuf);

  gemm_qkv8_k<<<dim3(12, 128), 512, 0, stream>>>(Xbf, Wqt, bq, bk, bv, Qh, Kh, Vt);

  attn3_k<<<dim3(cH, cBS, 4), 256, 0, stream>>>(Qh, Kh, Vt, rbuf, Ob);

  gemm_bt_k<<<dim3(8, 256), 256, 0, stream>>>(Ob, Wot, bo, out, cM, cD, cDWM);
}

// Round 7
// 539.955 us; speedup vs baseline: 1.7649x; 1.0082x over previous
//
#include <hip/hip_runtime.h>
#include <stdint.h>

typedef __bf16 bf16_t;
typedef __bf16 bf16x8 __attribute__((ext_vector_type(8)));
typedef __bf16 bf16x4 __attribute__((ext_vector_type(4)));
typedef float  f32x4  __attribute__((ext_vector_type(4)));

constexpr int cBS = 64, cP = 512, cD = 1024, cDWM = 1024, cH = 16, cHD = 64, cW = 128;
constexpr int cVTP = 672;           // padded p-extent of Vt (sp = p + 128, max used 656)
constexpr int cM = cBS * cP;        // 32768
constexpr float cSCALE = 0.125f;    // 1/sqrt(64)

__device__ __forceinline__ void gld_lds16(const void* g, void* l) {
#if __has_builtin(__builtin_amdgcn_global_load_lds)
  __builtin_amdgcn_global_load_lds(
      (__attribute__((address_space(1))) void*)g,
      (__attribute__((address_space(3))) void*)l, 16, 0, 0);
#else
  *(bf16x8*)l = *(const bf16x8*)g;
#endif
}

// ---------------------------------------------------------------------------
// fp32 -> bf16 conversion of X
__global__ void cvt_x_k(const float* __restrict__ X, bf16_t* __restrict__ Y, int n) {
  int i = (blockIdx.x * blockDim.x + threadIdx.x) * 4;
  if (i >= n) return;
  float4 v = *(const float4*)(X + i);
  bf16x4 o;
  o[0] = (bf16_t)v.x; o[1] = (bf16_t)v.y; o[2] = (bf16_t)v.z; o[3] = (bf16_t)v.w;
  *(bf16x4*)(Y + i) = o;
}

// transpose + convert the four 1024x1024 weights: W[k][n] fp32 -> Wt[n][k] bf16
__global__ void cvt_wt_k(const float* __restrict__ W0, const float* __restrict__ W1,
                         const float* __restrict__ W2, const float* __restrict__ W3,
                         bf16_t* __restrict__ T0, bf16_t* __restrict__ T1,
                         bf16_t* __restrict__ T2, bf16_t* __restrict__ T3) {
  __shared__ float tile[32][33];
  const float* Wsrc; bf16_t* Tdst;
  switch (blockIdx.z) {
    case 0: Wsrc = W0; Tdst = T0; break;
    case 1: Wsrc = W1; Tdst = T1; break;
    case 2: Wsrc = W2; Tdst = T2; break;
    default: Wsrc = W3; Tdst = T3; break;
  }
  const int n0 = blockIdx.x * 32, k0 = blockIdx.y * 32;
  const int c = threadIdx.x & 31, r8 = threadIdx.x >> 5;
#pragma unroll
  for (int q = 0; q < 4; ++q) {
    int row = r8 + q * 8;
    tile[row][c] = Wsrc[(size_t)(k0 + row) * 1024 + n0 + c];
  }
  __syncthreads();
#pragma unroll
  for (int q = 0; q < 4; ++q) {
    int row = r8 + q * 8;
    Tdst[(size_t)(n0 + row) * 1024 + k0 + c] = (bf16_t)tile[c][row];
  }
}

// r[b][t] = index of last reset at-or-before t (0 if none): parallel max-scan
__global__ void resets2_k(const int* __restrict__ mask, int* __restrict__ r) {
  __shared__ int sm[cP];
  const int b = blockIdx.x, t = threadIdx.x;
  sm[t] = mask[b * cP + t] ? t : 0;
  __syncthreads();
#pragma unroll
  for (int d = 1; d < cP; d <<= 1) {
    int u = (t >= d) ? sm[t - d] : 0;
    __syncthreads();
    if (u > sm[t]) sm[t] = u;
    __syncthreads();
  }
  r[b * cP + t] = sm[t];
}

// ---------------------------------------------------------------------------
// Fused QKV GEMM, 256x256 tile, 4 merged phases per 2 K-tiles.
// R7 change (the big one): NO explicit lgkmcnt(0) before the MFMAs -- the
// compiler inserts fine-grained per-register lgkmcnt(N) waits (m97 mechanism),
// so frag ds_reads stream INTO the MFMA block and the LDS pipe (~1150 cyc/CU/
// phase) overlaps the MFMA pipe (~1240 cyc) instead of adding to it. Also one
// barrier per phase (mid-phase barrier removed; drain algebra below).
// C[M][3072] = A[M][1024] * Wt[3072][1024]^T.
// Seg 0 -> Q head-major [b][h][p][hd], 1 -> K head-major, 2 -> Vt [b][h][hd][sp].
//
// LDS (128 KiB): per dbuf (64 KiB): A kh0 [0,16K) | A kh1 [16K,32K) |
//                                   B kh0 [32K,48K) | B kh1 [48K,64K)
// Each 16 KiB region: 256 rows x 32 bf16 in FRAGMENT ORDER (16 subtiles of
// 16 rows; element (row r, 16B k-chunk c) at subtile*1024 + (c*16+(r&15))*16)
// -> a wave's frag read covers 1024 consecutive bytes: 0 bank conflicts
// (verified R2). global_load_lds dest stays linear (tid*16); the GLOBAL
// source is permuted to match (rule #21).
//
// Phase(buf,kh): issue 4 B + 8 A frag reads; issue stage (4 gld_lds of one
// region); setprio(1); 32 MFMA (compiler-interleaved waits); setprio(0);
// counted vmcnt; s_barrier; sched_barrier(0).
// Hazards with ONE barrier/phase:
//  - reads of a region all have dependent MFMAs before the barrier => all
//    drained by barrier time (no explicit lgkm needed for the WAR hazard).
//  - each VM4 keeps exactly the newest 4 loads (this phase's stage) and
//    drains the region read NEXT phase, staged >=1 phase (~1600 cyc) earlier.
//  - a staged region was last READ >=2 phases earlier (>=2 barriers ago).
// Schedule per iteration (tiles j0=2t -> buf0, j1=2t+1 -> buf1):
//  A1 (0,kh0): stage (1,kh0,j1); VM4   A3 (1,kh0): stage (0,kh0,j2); VM4
//  A2 (0,kh1): stage (1,kh1,j1); VM4   A4 (1,kh1): stage (0,kh1,j2); VM4
__global__ __launch_bounds__(512, 2)
void gemm_qkv8_k(const bf16_t* __restrict__ A, const bf16_t* __restrict__ Wt,
                 const float* __restrict__ bq, const float* __restrict__ bk,
                 const float* __restrict__ bvv,
                 bf16_t* __restrict__ Qh, bf16_t* __restrict__ Kh,
                 bf16_t* __restrict__ Vt) {
  __shared__ __align__(16) char LDS[131072];
  const int tid = threadIdx.x;
  const int wid = tid >> 6, ln = tid & 63;
  const int ln15 = ln & 15, g4 = ln >> 4;
  const int wr = wid >> 2, wc = wid & 3;   // wave -> (row half, col quarter)

  // XCD swizzle: per-XCD m-slice, n-fastest so the A-panel stays L2-resident
  const int g = blockIdx.x + 12 * blockIdx.y;   // [0, 1536)
  const int xcd = g & 7, s = g >> 3;            // s in [0, 192)
  const int nb = s % 12, mloc = s / 12;         // mloc in [0, 16)
  const int m0 = (xcd * 16 + mloc) * 256, n0 = nb * 256;

  const bf16_t* Ab = A + (size_t)m0 * 1024;
  const bf16_t* Bb = Wt + (size_t)n0 * 1024;

  // staging: thread covers LDS chunks q = tid and q+512 of a 16 KiB region.
  // q -> subtile q>>6, row-in-subtile q&15, k-chunk (q>>4)&3
  // global element = ((q>>6)*16 + (q&15))*1024 + ((q>>4)&3)*8 (+128 rows @ +512)
  const int srow = (tid >> 6) * 16 + (tid & 15);    // 0..127
  const int kc = (tid >> 4) & 3;
  const size_t aoff = (size_t)srow * 1024 + (size_t)(kc * 8);
  char* const lbase = LDS + tid * 16;

  // frag read lane addressing: 1024 consecutive bytes per subtile
  const int lane16 = (g4 * 16 + ln15) * 16;
  const int abase = (wr * 8) * 1024 + lane16;   // + mi*1024, mi = 0..7
  const int bbase = (wc * 4) * 1024 + lane16;   // + nj*1024, within B region

  f32x4 acc[8][4];
#pragma unroll
  for (int i = 0; i < 8; ++i)
#pragma unroll
    for (int j = 0; j < 4; ++j) acc[i][j] = {0.f, 0.f, 0.f, 0.f};

#define STAGE_A(buf, kh, j) do {                                              \
    const bf16_t* gp_ = Ab + (size_t)((j) * 64 + (kh) * 32) + aoff;           \
    char* lp_ = lbase + (buf) * 65536 + (kh) * 16384;                         \
    gld_lds16(gp_, lp_);                                                      \
    gld_lds16(gp_ + (size_t)128 * 1024, lp_ + 8192);                          \
  } while (0)

#define STAGE_B(buf, kh, j) do {                                              \
    const bf16_t* gp_ = Bb + (size_t)((j) * 64 + (kh) * 32) + aoff;           \
    char* lp_ = lbase + (buf) * 65536 + (kh) * 16384 + 32768;                 \
    gld_lds16(gp_, lp_);                                                      \
    gld_lds16(gp_ + (size_t)128 * 1024, lp_ + 8192);                          \
  } while (0)

#define NOSTAGE ((void)0)
#define VM4 asm volatile("s_waitcnt vmcnt(4)" ::: "memory")
#define VM0 asm volatile("s_waitcnt vmcnt(0)" ::: "memory")
#define NOVM ((void)0)

// One phase: issue all 12 frag reads (B first, then A in MFMA order), issue
// the stage, then MFMA with COMPILER-inserted fine-grained lgkm waits.
// One barrier at phase end; sched_barrier pins next phase's reads after it.
#define PHASE(buf, kh, STAGE, VME) do {                                       \
    const char* Ar_ = LDS + (buf) * 65536 + (kh) * 16384 + abase;             \
    const char* Br_ = LDS + (buf) * 65536 + (kh) * 16384 + 32768 + bbase;     \
    bf16x8 af_[8], bf_[4];                                                    \
    _Pragma("unroll")                                                         \
    for (int nj_ = 0; nj_ < 4; ++nj_)                                         \
      bf_[nj_] = *(const bf16x8*)(Br_ + nj_ * 1024);                          \
    _Pragma("unroll")                                                         \
    for (int mi_ = 0; mi_ < 8; ++mi_)                                         \
      af_[mi_] = *(const bf16x8*)(Ar_ + mi_ * 1024);                          \
    STAGE;                                                                    \
    __builtin_amdgcn_s_setprio(1);                                            \
    _Pragma("unroll")                                                         \
    for (int mi_ = 0; mi_ < 8; ++mi_)                                         \
      _Pragma("unroll")                                                       \
      for (int nj_ = 0; nj_ < 4; ++nj_)                                       \
        acc[mi_][nj_] = __builtin_amdgcn_mfma_f32_16x16x32_bf16(              \
            af_[mi_], bf_[nj_], acc[mi_][nj_], 0, 0, 0);                      \
    __builtin_amdgcn_s_setprio(0);                                            \
    VME;                                                                      \
    __builtin_amdgcn_s_barrier();                                             \
    __builtin_amdgcn_sched_barrier(0);                                        \
  } while (0)

  // prologue: tile0 both regions (8 loads); drain kh0's 4 (keep kh1 in flight)
  STAGE_A(0, 0, 0); STAGE_B(0, 0, 0);
  STAGE_A(0, 1, 0); STAGE_B(0, 1, 0);
  VM4;
  __builtin_amdgcn_s_barrier();
  __builtin_amdgcn_sched_barrier(0);

  for (int t = 0; t < 7; ++t) {
    const int j1 = 2 * t + 1, j2 = 2 * t + 2;
    PHASE(0, 0, { STAGE_A(1, 0, j1); STAGE_B(1, 0, j1); }, VM4);
    PHASE(0, 1, { STAGE_A(1, 1, j1); STAGE_B(1, 1, j1); }, VM4);
    PHASE(1, 0, { STAGE_A(0, 0, j2); STAGE_B(0, 0, j2); }, VM4);
    PHASE(1, 1, { STAGE_A(0, 1, j2); STAGE_B(0, 1, j2); }, VM4);
  }
  // tail: tiles 14,15; only tile15 still needs staging
  PHASE(0, 0, { STAGE_A(1, 0, 15); STAGE_B(1, 0, 15); }, VM4);
  PHASE(0, 1, { STAGE_A(1, 1, 15); STAGE_B(1, 1, 15); }, VM4);
  PHASE(1, 0, NOSTAGE, VM0);
  PHASE(1, 1, NOSTAGE, NOVM);

#undef PHASE
#undef STAGE_A
#undef STAGE_B

  const int seg = n0 >> 10;                      // block-uniform: 0=Q 1=K 2=V
  const float* bias = (seg == 0) ? bq : (seg == 1) ? bk : bvv;
  bf16_t* QK = (seg == 0) ? Qh : Kh;
#pragma unroll
  for (int mi = 0; mi < 8; ++mi) {
    const int rbase = m0 + wr * 128 + mi * 16 + g4 * 4;
    const int b = rbase >> 9, pb = rbase & 511;
#pragma unroll
    for (int nj = 0; nj < 4; ++nj) {
      const int col = n0 + wc * 64 + nj * 16 + ln15;
      const int cl = col & 1023;
      const int h = cl >> 6, hd = cl & 63;
      const float bv = bias[cl];
      if (seg < 2) {
        // head-major: [b][h][p][hd]
#pragma unroll
        for (int r = 0; r < 4; ++r)
          QK[(((size_t)(b * cH + h)) * cP + pb + r) * cHD + hd] =
              (bf16_t)(acc[mi][nj][r] + bv);
      } else {
        bf16x4 pk;
#pragma unroll
        for (int r = 0; r < 4; ++r) pk[r] = (bf16_t)(acc[mi][nj][r] + bv);
        *(bf16x4*)(Vt + ((size_t)((b * cH + h) * cHD + hd)) * cVTP + 128 + pb) = pk;
      }
    }
  }
}

// Output-projection GEMM (fp32 out), 128x128 tile + XCD swizzle
__global__ __launch_bounds__(256)
void gemm_bt_k(const bf16_t* __restrict__ A, const bf16_t* __restrict__ Bt,
               const float* __restrict__ bias, float* __restrict__ C,
               int M, int N, int K) {
  __shared__ __align__(16) bf16_t As[2][128 * 32];
  __shared__ __align__(16) bf16_t Bs[2][128 * 32];
  const int tid = threadIdx.x;
  const int wv = tid >> 6, ln = tid & 63;
  const int ln15 = ln & 15, g4 = ln >> 4;

  const int g = blockIdx.x + 8 * blockIdx.y;    // [0, 2048)
  const int xcd = g & 7, s = g >> 3;            // s in [0, 256)
  const int nb = s & 7, mloc = s >> 3;          // mloc in [0, 32)
  const int m0 = (xcd * 32 + mloc) * 128, n0 = nb * 128;

  const int wm = (wv >> 1) * 64, wn = (wv & 1) * 64;
  const bf16_t* Ab = A + (size_t)m0 * K;
  const bf16_t* Bb = Bt + (size_t)n0 * K;

  auto stage = [&](const bf16_t* G, bf16_t* L, int k0) {
#pragma unroll
    for (int gg = 0; gg < 2; ++gg) {
      int slot = gg * 256 + tid;
      gld_lds16(G + (size_t)(slot >> 2) * K + (k0 + (slot & 3) * 8), L + slot * 8);
    }
  };

  f32x4 acc[4][4];
#pragma unroll
  for (int i = 0; i < 4; ++i)
#pragma unroll
    for (int j = 0; j < 4; ++j) acc[i][j] = {0.f, 0.f, 0.f, 0.f};

  const int nk = K >> 5;
  stage(Ab, As[0], 0);
  stage(Bb, Bs[0], 0);
  for (int kt = 0; kt < nk; ++kt) {
    __syncthreads();
    if (kt + 1 < nk) {
      stage(Ab, As[(kt + 1) & 1], (kt + 1) * 32);
      stage(Bb, Bs[(kt + 1) & 1], (kt + 1) * 32);
    }
    const bf16_t* Asb = As[kt & 1];
    const bf16_t* Bsb = Bs[kt & 1];
    bf16x8 af[4], bfr[4];
#pragma unroll
    for (int i = 0; i < 4; ++i)
      af[i] = *(const bf16x8*)(Asb + (wm + i * 16 + ln15) * 32 + g4 * 8);
#pragma unroll
    for (int j = 0; j < 4; ++j)
      bfr[j] = *(const bf16x8*)(Bsb + (wn + j * 16 + ln15) * 32 + g4 * 8);
#pragma unroll
    for (int i = 0; i < 4; ++i)
#pragma unroll
      for (int j = 0; j < 4; ++j)
        acc[i][j] = __builtin_amdgcn_mfma_f32_16x16x32_bf16(af[i], bfr[j], acc[i][j], 0, 0, 0);
  }

#pragma unroll
  for (int i = 0; i < 4; ++i) {
    const int rbase = m0 + wm + i * 16 + g4 * 4;
#pragma unroll
    for (int j = 0; j < 4; ++j) {
      const int col = n0 + wn + j * 16 + ln15;
      const float bv = bias[col];
#pragma unroll
      for (int r = 0; r < 4; ++r)
        C[(size_t)(rbase + r) * N + col] = acc[i][j][r] + bv;
    }
  }
}

// ---------------------------------------------------------------------------
// Windowed attention v3: block = (head, batch, t-chunk); 4 waves each own a
// 16-token tile; 2 iterations cover the 128-token chunk. Q/K head-major.
__global__ __launch_bounds__(256)
void attn3_k(const bf16_t* __restrict__ Q, const bf16_t* __restrict__ Kv,
             const bf16_t* __restrict__ Vt, const int* __restrict__ rr,
             bf16_t* __restrict__ O) {
  __shared__ __align__(16) bf16_t Pl[4][16][168];
  const int tid = threadIdx.x;
  const int wv = tid >> 6, ln = tid & 63, ln15 = ln & 15, g4 = ln >> 4;
  const int h = blockIdx.x, b = blockIdx.y, tc = blockIdx.z;
  bf16_t(*Pw)[168] = Pl[wv];
  const bf16_t* vb = Vt + ((size_t)(b * cH + h)) * cHD * cVTP;
  const bf16_t* qb = Q + ((size_t)(b * cH + h)) * cP * cHD;
  const bf16_t* kb = Kv + ((size_t)(b * cH + h)) * cP * cHD;

  for (int sub = 0; sub < 2; ++sub) {
    const int t0 = (tc * 2 + sub) * 64 + wv * 16;
    const int sbase = t0 - 128;

    int rv[4];
#pragma unroll
    for (int r = 0; r < 4; ++r) rv[r] = rr[b * cP + t0 + g4 * 4 + r];

    // Q A-frag: m = ln15 (t), k = g4*8+j (hd)
    const bf16_t* qp = qb + (size_t)(t0 + ln15) * cHD + g4 * 8;
    const bf16x8 qa0 = *(const bf16x8*)qp;
    const bf16x8 qa1 = *(const bf16x8*)(qp + 32);

    // QK^T over 9 s-chunks of 16 (s in [t0-128, t0+15])
    f32x4 lg[9];
#pragma unroll
    for (int c = 0; c < 9; ++c) {
      const int s = sbase + c * 16 + ln15;  // B-frag n = ln15 (s), k = hd
      bf16x8 k0v, k1v;
      if ((unsigned)s < (unsigned)cP) {
        const bf16_t* kp = kb + (size_t)s * cHD + g4 * 8;
        k0v = *(const bf16x8*)kp;
        k1v = *(const bf16x8*)(kp + 32);
      } else {
#pragma unroll
        for (int z = 0; z < 8; ++z) { k0v[z] = (bf16_t)0.f; k1v[z] = (bf16_t)0.f; }
      }
      f32x4 a = {0.f, 0.f, 0.f, 0.f};
      a = __builtin_amdgcn_mfma_f32_16x16x32_bf16(qa0, k0v, a, 0, 0, 0);
      a = __builtin_amdgcn_mfma_f32_16x16x32_bf16(qa1, k1v, a, 0, 0, 0);
      lg[c] = a;
    }

    // mask + scale; C layout: col(s)=ln15, row(t)=g4*4+reg
    float mx[4] = {-1e30f, -1e30f, -1e30f, -1e30f};
#pragma unroll
    for (int c = 0; c < 9; ++c)
#pragma unroll
      for (int r = 0; r < 4; ++r) {
        const int s = sbase + c * 16 + ln15;
        const int t = t0 + g4 * 4 + r;
        const bool ok = (s >= rv[r]) && (s <= t) && (t - s < cW);
        const float l = ok ? lg[c][r] * cSCALE : -1e30f;
        lg[c][r] = l;
        mx[r] = fmaxf(mx[r], l);
      }
#pragma unroll
    for (int r = 0; r < 4; ++r) {
      mx[r] = fmaxf(mx[r], __shfl_xor(mx[r], 1));
      mx[r] = fmaxf(mx[r], __shfl_xor(mx[r], 2));
      mx[r] = fmaxf(mx[r], __shfl_xor(mx[r], 4));
      mx[r] = fmaxf(mx[r], __shfl_xor(mx[r], 8));
    }
    float sm[4] = {0.f, 0.f, 0.f, 0.f};
#pragma unroll
    for (int c = 0; c < 9; ++c)
#pragma unroll
      for (int r = 0; r < 4; ++r) {
        const float e = __expf(lg[c][r] - mx[r]);
        lg[c][r] = e;
        sm[r] += e;
      }
#pragma unroll
    for (int r = 0; r < 4; ++r) {
      sm[r] += __shfl_xor(sm[r], 1);
      sm[r] += __shfl_xor(sm[r], 2);
      sm[r] += __shfl_xor(sm[r], 4);
      sm[r] += __shfl_xor(sm[r], 8);
    }
    float inv[4];
#pragma unroll
    for (int r = 0; r < 4; ++r) inv[r] = 1.f / sm[r];

    // P -> LDS (C-layout write), zero pad cols 144..159 for the 5th PV chunk
#pragma unroll
    for (int c = 0; c < 9; ++c)
#pragma unroll
      for (int r = 0; r < 4; ++r)
        Pw[g4 * 4 + r][c * 16 + ln15] = (bf16_t)(lg[c][r] * inv[r]);
#pragma unroll
    for (int z = 0; z < 4; ++z)
      Pw[ln15][144 + g4 * 4 + z] = (bf16_t)0.f;

    // PV: A = P (m=t, k=s from LDS), B = Vt rows (n=hd, k=s contiguous)
    f32x4 oacc[4];
#pragma unroll
    for (int j = 0; j < 4; ++j) oacc[j] = {0.f, 0.f, 0.f, 0.f};
#pragma unroll
    for (int c2 = 0; c2 < 5; ++c2) {
      const bf16x8 pa = *(const bf16x8*)(&Pw[ln15][c2 * 32 + g4 * 8]);
#pragma unroll
      for (int j = 0; j < 4; ++j) {
        const bf16x8 vf =
            *(const bf16x8*)(vb + (size_t)(j * 16 + ln15) * cVTP + (t0 + c2 * 32 + g4 * 8));
        oacc[j] = __builtin_amdgcn_mfma_f32_16x16x32_bf16(pa, vf, oacc[j], 0, 0, 0);
      }
    }
#pragma unroll
    for (int j = 0; j < 4; ++j) {
      const int col = h * cHD + j * 16 + ln15;
#pragma unroll
      for (int r = 0; r < 4; ++r)
        O[((size_t)(b * cP + t0 + g4 * 4 + r)) * cDWM + col] = (bf16_t)oacc[j][r];
    }
  }
}

// ---------------------------------------------------------------------------
extern "C" void kernel_launch(void* const* d_in, const int* in_sizes, int n_in,
                              void* d_out, int out_size, void* d_ws, size_t ws_size,
                              hipStream_t stream) {
  (void)in_sizes; (void)n_in; (void)out_size; (void)ws_size;
  const float* x  = (const float*)d_in[0];
  const int* mask = (const int*)d_in[1];
  const float* Wq = (const float*)d_in[2];
  const float* bq = (const float*)d_in[3];
  const float* Wk = (const float*)d_in[4];
  const float* bk = (const float*)d_in[5];
  const float* Wv = (const float*)d_in[6];
  const float* bv = (const float*)d_in[7];
  const float* Wo = (const float*)d_in[8];
  const float* bo = (const float*)d_in[9];
  float* out = (float*)d_out;

  char* ws = (char*)d_ws;
  size_t off = 0;
  bf16_t* Xbf = (bf16_t*)(ws + off); off += (size_t)cM * cD * 2;          // 64 MiB
  bf16_t* Wqt = (bf16_t*)(ws + off); off += (size_t)cD * cDWM * 2;        // contiguous
  bf16_t* Wkt = (bf16_t*)(ws + off); off += (size_t)cD * cDWM * 2;        //   [3072][1024]
  bf16_t* Wvt = (bf16_t*)(ws + off); off += (size_t)cD * cDWM * 2;        //   QKV block
  bf16_t* Wot = (bf16_t*)(ws + off); off += (size_t)cDWM * cD * 2;
  bf16_t* Qh  = (bf16_t*)(ws + off); off += (size_t)cM * cDWM * 2;        // 64 MiB
  bf16_t* Kh  = (bf16_t*)(ws + off); off += (size_t)cM * cDWM * 2;        // 64 MiB
  bf16_t* Vt  = (bf16_t*)(ws + off); off += (size_t)cBS * cH * cHD * cVTP * 2;  // 84 MiB
  int* rbuf   = (int*)(ws + off);    off += (size_t)cBS * cP * 4;
  bf16_t* Ob  = Xbf;  // X no longer needed after the QKV projection

  cvt_x_k<<<(cM * cD / 4 + 255) / 256, 256, 0, stream>>>(x, Xbf, cM * cD);
  cvt_wt_k<<<dim3(32, 32, 4), 256, 0, stream>>>(Wq, Wk, Wv, Wo, Wqt, Wkt, Wvt, Wot);
  resets2_k<<<cBS, cP, 0, stream>>>(mask, rbuf);

  gemm_qkv8_k<<<dim3(12, 128), 512, 0, stream>>>(Xbf, Wqt, bq, bk, bv, Qh, Kh, Vt);

  attn3_k<<<dim3(cH, cBS, 4), 256, 0, stream>>>(Qh, Kh, Vt, rbuf, Ob);

  gemm_bt_k<<<dim3(8, 256), 256, 0, stream>>>(Ob, Wot, bo, out, cM, cD, cDWM);
}